// Round 1
// baseline (1859.946 us; speedup 1.0000x reference)
//
#include <hip/hip_runtime.h>

typedef unsigned short u16;
typedef __attribute__((ext_vector_type(8))) short bf16x8;   // 8 bf16 (4 VGPR) MFMA frag
typedef __attribute__((ext_vector_type(8))) unsigned short us8;
typedef __attribute__((ext_vector_type(4))) unsigned short us4;
typedef __attribute__((ext_vector_type(4))) float f32x4;

#define SEQ    1024
#define TOK    2048           // B*S
#define HID    1024
#define NLAYER 6
#define NHEAD  16
#define HDIM   64
#define QKV3   3072
#define INTER  2730
#define IPAD   2816
#define VOCAB  32000
#define LN_EPS 1e-5f

__device__ __forceinline__ u16 f2bf(float f) {
  unsigned u = __float_as_uint(f);
  return (u16)((u + 0x7fffu + ((u >> 16) & 1u)) >> 16);   // RNE
}
__device__ __forceinline__ float bf2f(u16 u) {
  return __uint_as_float(((unsigned)u) << 16);
}

__device__ __forceinline__ void gl_lds16(const void* g, void* l) {
  __builtin_amdgcn_global_load_lds(
      (const __attribute__((address_space(1))) void*)g,
      (__attribute__((address_space(3))) void*)l, 16, 0, 0);
}

// ---------------- embedding: h = tok_emb[id] + pos_emb[s] (f32) ----------------
__global__ __launch_bounds__(256) void embed_kernel(
    const int* __restrict__ ids, const float* __restrict__ tok,
    const float* __restrict__ pos, float* __restrict__ h)
{
  int t = blockIdx.x;
  int s = t & (SEQ - 1);
  int id = ids[t];
  int c = threadIdx.x * 4;
  float4 tv = *(const float4*)(tok + (long)id * HID + c);
  float4 pv = *(const float4*)(pos + (long)s * HID + c);
  float4 o;
  o.x = tv.x + pv.x; o.y = tv.y + pv.y; o.z = tv.z + pv.z; o.w = tv.w + pv.w;
  *(float4*)(h + (long)t * HID + c) = o;
}

// ---------------- layernorm: f32 in -> bf16 out ----------------
__global__ __launch_bounds__(256) void ln_kernel(
    const float* __restrict__ h, const float* __restrict__ w,
    const float* __restrict__ b, u16* __restrict__ out)
{
  int t = blockIdx.x;
  int tid = threadIdx.x;
  int lane = tid & 63, wid = tid >> 6;
  float4 v = *(const float4*)(h + (long)t * HID + tid * 4);
  float s1 = v.x + v.y + v.z + v.w;
  float s2 = v.x * v.x + v.y * v.y + v.z * v.z + v.w * v.w;
#pragma unroll
  for (int o = 32; o > 0; o >>= 1) { s1 += __shfl_down(s1, o); s2 += __shfl_down(s2, o); }
  __shared__ float r1[4], r2[4];
  if (lane == 0) { r1[wid] = s1; r2[wid] = s2; }
  __syncthreads();
  float t1 = r1[0] + r1[1] + r1[2] + r1[3];
  float t2 = r2[0] + r2[1] + r2[2] + r2[3];
  float mu = t1 * (1.f / HID);
  float var = t2 * (1.f / HID) - mu * mu;
  float rs = rsqrtf(var + LN_EPS);
  float4 wv = *(const float4*)(w + tid * 4);
  float4 bv = *(const float4*)(b + tid * 4);
  us4 o4;
  o4[0] = f2bf((v.x - mu) * rs * wv.x + bv.x);
  o4[1] = f2bf((v.y - mu) * rs * wv.y + bv.y);
  o4[2] = f2bf((v.z - mu) * rs * wv.z + bv.z);
  o4[3] = f2bf((v.w - mu) * rs * wv.w + bv.w);
  *(us4*)(out + (long)t * HID + tid * 4) = o4;
}

// ---------------- f32 -> bf16 weight convert with zero padding ----------------
__global__ __launch_bounds__(256) void cvt_kernel(
    const float* __restrict__ src, u16* __restrict__ dst,
    int N, int K, int Kpad, long total8)
{
  long i = (long)blockIdx.x * 256 + threadIdx.x;
  if (i >= total8) return;
  int kp8 = Kpad >> 3;
  int n = (int)(i / kp8);
  int kc = (int)(i % kp8);
  us8 o;
#pragma unroll
  for (int j = 0; j < 8; ++j) {
    int k = kc * 8 + j;
    float v = (n < N && k < K) ? src[(long)n * K + k] : 0.f;
    o[j] = f2bf(v);
  }
  *(us8*)(dst + i * 8) = o;
}

// ---------------- V transpose: vT[z][d][k] = qkv[b][k][2048 + h*64 + d] ----------------
__global__ __launch_bounds__(256) void vtrans_kernel(
    const u16* __restrict__ qkv, u16* __restrict__ vT)
{
  int gid = blockIdx.x * 256 + threadIdx.x;     // 32*64*128 total
  int d  = gid & 63;
  int kc = (gid >> 6) & 127;
  int z  = gid >> 13;                           // b*16+h
  int b = z >> 4, hh = z & 15;
  const u16* src = qkv + (long)b * SEQ * QKV3 + 2048 + hh * 64 + d;
  us8 v;
#pragma unroll
  for (int j = 0; j < 8; ++j) v[j] = src[(long)(kc * 8 + j) * QKV3];
  *(us8*)(vT + (long)z * 65536 + (long)d * 1024 + kc * 8) = v;
}

// ---------------- softmax in-place over bf16 rows of 1024 (one wave per row) ----------------
__global__ __launch_bounds__(256) void softmax_kernel(u16* __restrict__ sc)
{
  int row = blockIdx.x * 4 + (threadIdx.x >> 6);
  int lane = threadIdx.x & 63;
  u16* p = sc + (long)row * 1024 + lane * 16;
  us8 a = *(us8*)p;
  us8 b = *(us8*)(p + 8);
  float f[16];
#pragma unroll
  for (int j = 0; j < 8; ++j) { f[j] = bf2f(a[j]); f[8 + j] = bf2f(b[j]); }
  float m = f[0];
#pragma unroll
  for (int j = 1; j < 16; ++j) m = fmaxf(m, f[j]);
#pragma unroll
  for (int o = 1; o < 64; o <<= 1) m = fmaxf(m, __shfl_xor(m, o));
  float s = 0.f;
#pragma unroll
  for (int j = 0; j < 16; ++j) { f[j] = __expf(f[j] - m); s += f[j]; }
#pragma unroll
  for (int o = 1; o < 64; o <<= 1) s += __shfl_xor(s, o);
  float inv = 1.f / s;
#pragma unroll
  for (int j = 0; j < 8; ++j) { a[j] = f2bf(f[j] * inv); b[j] = f2bf(f[8 + j] * inv); }
  *(us8*)p = a;
  *(us8*)(p + 8) = b;
}

// ---------------- silu(gate)*up -> y (bf16) ----------------
__global__ __launch_bounds__(256) void silumul_kernel(
    const u16* __restrict__ gu, u16* __restrict__ y)
{
  long i = (long)blockIdx.x * 256 + threadIdx.x;   // TOK * IPAD/8
  int s = (int)(i / (IPAD / 8));
  int c8 = (int)(i % (IPAD / 8));
  const u16* base = gu + (long)s * (2 * IPAD) + c8 * 8;
  us8 g = *(const us8*)base;
  us8 u = *(const us8*)(base + IPAD);
  us8 o;
#pragma unroll
  for (int j = 0; j < 8; ++j) {
    float gf = bf2f(g[j]);
    float uf = bf2f(u[j]);
    float r = gf / (1.f + __expf(-gf)) * uf;
    o[j] = f2bf(r);
  }
  *(us8*)(y + i * 8) = o;
}

// ---------------- GEMM: C[m,n] = scale * sum_k A[m,k]*B[n,k] (+resid) ----------------
// A: [M][K] bf16 row-major (lda), B: [N][K] bf16 row-major (ldb).
// EPI: 0 = bf16 out (xscale), 1 = f32 out (xscale), 2 = f32 resid add.
// Batched via blockIdx.z: off = (z/bdiv)*s1 + (z%bdiv)*s2 per matrix.
template<int BM, int BN, int EPI>
__global__ __launch_bounds__(256) void gemm_bt(
    const u16* __restrict__ A, const u16* __restrict__ B,
    void* __restrict__ Cv, const float* __restrict__ resid,
    int lda, int ldb, int ldc, int K, float scale, int bdiv,
    long sA1, long sA2, long sB1, long sB2, long sC1, long sC2)
{
  constexpr int FM = BM / 32;   // frags per wave in M (wave tile = BM/2)
  constexpr int FN = BN / 32;
  __shared__ u16 As[2][BM * 32];
  __shared__ u16 Bs[2][BN * 32];

  const int tid = threadIdx.x;
  const int lane = tid & 63;
  const int wid = tid >> 6;
  const int wm = wid >> 1, wn = wid & 1;

  const int z = blockIdx.z;
  const long offA = (long)(z / bdiv) * sA1 + (long)(z % bdiv) * sA2;
  const long offB = (long)(z / bdiv) * sB1 + (long)(z % bdiv) * sB2;
  const long offC = (long)(z / bdiv) * sC1 + (long)(z % bdiv) * sC2;

  const u16* Ab = A + offA + (long)blockIdx.x * BM * lda;
  const u16* Bb = B + offB + (long)blockIdx.y * BN * ldb;

  auto stage = [&](int buf, int kt) {
    const u16* a = Ab + (long)kt * 32;
    const u16* bsrc = Bb + (long)kt * 32;
#pragma unroll
    for (int i = 0; i < BM / 64; ++i) {
      int row = i * 64 + wid * 16 + (lane >> 2);
      gl_lds16(a + (long)row * lda + (lane & 3) * 8, &As[buf][i * 2048 + wid * 512]);
    }
#pragma unroll
    for (int i = 0; i < BN / 64; ++i) {
      int row = i * 64 + wid * 16 + (lane >> 2);
      gl_lds16(bsrc + (long)row * ldb + (lane & 3) * 8, &Bs[buf][i * 2048 + wid * 512]);
    }
  };

  f32x4 acc[FM][FN];
#pragma unroll
  for (int i = 0; i < FM; ++i)
#pragma unroll
    for (int j = 0; j < FN; ++j) acc[i][j] = (f32x4){0.f, 0.f, 0.f, 0.f};

  int aoff[FM], boff[FN];
#pragma unroll
  for (int i = 0; i < FM; ++i)
    aoff[i] = (wm * (BM / 2) + i * 16 + (lane & 15)) * 32 + (lane >> 4) * 8;
#pragma unroll
  for (int j = 0; j < FN; ++j)
    boff[j] = (wn * (BN / 2) + j * 16 + (lane & 15)) * 32 + (lane >> 4) * 8;

  const int KT = K >> 5;
  stage(0, 0);
  __syncthreads();
  int cur = 0;
  for (int kt = 0; kt < KT; ++kt) {
    if (kt + 1 < KT) stage(cur ^ 1, kt + 1);
    bf16x8 av[FM], bv[FN];
#pragma unroll
    for (int i = 0; i < FM; ++i) av[i] = *(const bf16x8*)&As[cur][aoff[i]];
#pragma unroll
    for (int j = 0; j < FN; ++j) bv[j] = *(const bf16x8*)&Bs[cur][boff[j]];
#pragma unroll
    for (int i = 0; i < FM; ++i)
#pragma unroll
      for (int j = 0; j < FN; ++j)
        acc[i][j] = __builtin_amdgcn_mfma_f32_16x16x32_bf16(av[i], bv[j], acc[i][j], 0, 0, 0);
    __syncthreads();
    cur ^= 1;
  }

  const int r0 = blockIdx.x * BM + wm * (BM / 2) + (lane >> 4) * 4;
  const int c0 = blockIdx.y * BN + wn * (BN / 2) + (lane & 15);
#pragma unroll
  for (int i = 0; i < FM; ++i) {
#pragma unroll
    for (int j = 0; j < FN; ++j) {
      f32x4 v = acc[i][j];
#pragma unroll
      for (int r = 0; r < 4; ++r) {
        long idx = offC + (long)(r0 + i * 16 + r) * ldc + (c0 + j * 16);
        if (EPI == 0)       ((u16*)Cv)[idx] = f2bf(v[r] * scale);
        else if (EPI == 1)  ((float*)Cv)[idx] = v[r] * scale;
        else                ((float*)Cv)[idx] = resid[idx] + v[r];
      }
    }
  }
}

// ---------------- gemm256: 256x256 tile, BK=32, 512 thr, deep pipeline ----------------
// C[m,n] = sum_k A[m,k]*B[n,k].  A:[2048][1024] bf16, B:[256*NB][1024] bf16.
// Grid: 8*NB flat blocks, XCD-bijective swizzle, M-fastest within XCD chunk.
// 4 LDS buffers (128 KiB), prefetch depth 3 K-tiles, counted vmcnt(8) at tile
// boundaries (never 0 in steady state).  LDS layout K-major [kgroup][row][16B]
// -> ds_read_b128 fragments hit each bank exactly 8x (b128 minimum, no XOR).
// EPI: 0 = bf16 out, 1 = f32 out.
template<int EPI>
__global__ __launch_bounds__(512, 2) void gemm256(
    const u16* __restrict__ A, const u16* __restrict__ B,
    void* __restrict__ Cv, int NB, int ldc)
{
  __shared__ u16 lds[4][2][4][256][8];   // [buf][A|B][kgroup][row][8 bf16] = 128 KiB

  const int tid  = threadIdx.x;
  const int lane = tid & 63;
  const int w    = tid >> 6;           // 0..7
  const int wm   = w >> 2;             // 0..1
  const int wn   = w & 3;              // 0..3

  const int flat = blockIdx.x;                     // 0 .. 8*NB-1
  const int swz  = (flat & 7) * NB + (flat >> 3);  // bijective (nwg % 8 == 0)
  const int bm   = swz & 7;
  const int bn   = swz >> 3;

  const u16* Ab = A + (long)bm * 256 * 1024;
  const u16* Bb = B + (long)bn * 256 * 1024;

  // stage one matrix of K-tile t into buf: 2 x global_load_lds(16B) per thread.
  // unit u = w*2+i in 0..15 -> (kgroup u&3, rowgroup u>>2); LDS dest is
  // wave-uniform base, HW adds lane*16 -> row rg*64+lane.  Global src is
  // per-lane: row (rg*64+lane), k-bytes (t*32 + g*8)*2.
  auto stage = [&](int mat, int buf, int t) {
#pragma unroll
    for (int i = 0; i < 2; ++i) {
      const int u  = w * 2 + i;
      const int g  = u & 3;
      const int rg = u >> 2;
      const u16* src = (mat == 0 ? Ab : Bb)
                     + (long)(rg * 64 + lane) * 1024 + t * 32 + g * 8;
      gl_lds16(src, &lds[buf][mat][g][rg * 64][0]);
    }
  };

  f32x4 acc[2][4][4];
#pragma unroll
  for (int q = 0; q < 2; ++q)
#pragma unroll
    for (int f = 0; f < 4; ++f)
#pragma unroll
      for (int n = 0; n < 4; ++n) acc[q][f][n] = (f32x4){0.f, 0.f, 0.f, 0.f};

  const int arow = lane & 15;   // row-within-fragment
  const int kg   = lane >> 4;   // k-group (8 bf16 each)

  // prologue: stage K-tiles 0,1,2 (12 loads) -> drain tile0 (vmcnt(8)).
  stage(0, 0, 0); stage(1, 0, 0);
  stage(0, 1, 1); stage(1, 1, 1);
  stage(0, 2, 2); stage(1, 2, 2);
  asm volatile("s_waitcnt vmcnt(8)" ::: "memory");
  asm volatile("s_barrier" ::: "memory");

  const int KT = 1024 / 32;   // 32 K-tiles
#pragma unroll 4
  for (int t = 0; t < KT; ++t) {
    const int cb = t & 3;
    const int pb = (t + 3) & 3;
    const bool pf = (t + 3 < KT);

    bf16x8 av[4], bv[4];
    // ---- phase 0: m-half 0 (8 ds_read_b128) + stage A of t+3 ----
#pragma unroll
    for (int f = 0; f < 4; ++f)
      av[f] = *(const bf16x8*)&lds[cb][0][kg][wm * 128 + f * 16 + arow][0];
#pragma unroll
    for (int n = 0; n < 4; ++n)
      bv[n] = *(const bf16x8*)&lds[cb][1][kg][wn * 64 + n * 16 + arow][0];
    if (pf) stage(0, pb, t + 3);
    asm volatile("s_barrier" ::: "memory");
    __builtin_amdgcn_s_setprio(1);
#pragma unroll
    for (int f = 0; f < 4; ++f)
#pragma unroll
      for (int n = 0; n < 4; ++n)
        acc[0][f][n] = __builtin_amdgcn_mfma_f32_16x16x32_bf16(av[f], bv[n], acc[0][f][n], 0, 0, 0);
    __builtin_amdgcn_s_setprio(0);
    asm volatile("s_barrier" ::: "memory");

    // ---- phase 1: m-half 1 (4 ds_read_b128, B reused) + stage B of t+3 ----
#pragma unroll
    for (int f = 0; f < 4; ++f)
      av[f] = *(const bf16x8*)&lds[cb][0][kg][wm * 128 + 64 + f * 16 + arow][0];
    if (pf) stage(1, pb, t + 3);
    asm volatile("s_barrier" ::: "memory");
    __builtin_amdgcn_s_setprio(1);
#pragma unroll
    for (int f = 0; f < 4; ++f)
#pragma unroll
      for (int n = 0; n < 4; ++n)
        acc[1][f][n] = __builtin_amdgcn_mfma_f32_16x16x32_bf16(av[f], bv[n], acc[1][f][n], 0, 0, 0);
    __builtin_amdgcn_s_setprio(0);

    // tile-boundary wait: drain tile t+1, keep t+2/t+3 (8 loads) in flight.
    if (t + 3 < KT)      asm volatile("s_waitcnt vmcnt(8)" ::: "memory");
    else if (t + 2 < KT) asm volatile("s_waitcnt vmcnt(4)" ::: "memory");
    else                 asm volatile("s_waitcnt vmcnt(0)" ::: "memory");
    asm volatile("s_barrier" ::: "memory");
  }

  // epilogue
#pragma unroll
  for (int q = 0; q < 2; ++q) {
#pragma unroll
    for (int f = 0; f < 4; ++f) {
      const int r0 = bm * 256 + wm * 128 + q * 64 + f * 16 + kg * 4;
#pragma unroll
      for (int n = 0; n < 4; ++n) {
        const int c = bn * 256 + wn * 64 + n * 16 + arow;
        f32x4 v = acc[q][f][n];
#pragma unroll
        for (int r = 0; r < 4; ++r) {
          long idx = (long)(r0 + r) * ldc + c;
          if (EPI == 0) ((u16*)Cv)[idx] = f2bf(v[r]);
          else          ((float*)Cv)[idx] = v[r];
        }
      }
    }
  }
}

extern "C" void kernel_launch(void* const* d_in, const int* in_sizes, int n_in,
                              void* d_out, int out_size, void* d_ws, size_t ws_size,
                              hipStream_t stream)
{
  (void)in_sizes; (void)n_in; (void)out_size; (void)ws_size;
  const int*   ids     = (const int*)d_in[0];
  const float* tok_emb = (const float*)d_in[1];
  const float* pos_emb = (const float*)d_in[2];
  const float* qkv_w   = (const float*)d_in[3];
  const float* o_w     = (const float*)d_in[4];
  const float* gate_w  = (const float*)d_in[5];
  const float* up_w    = (const float*)d_in[6];
  const float* down_w  = (const float*)d_in[7];
  const float* ln1_w   = (const float*)d_in[8];
  const float* ln1_b   = (const float*)d_in[9];
  const float* ln2_w   = (const float*)d_in[10];
  const float* ln2_b   = (const float*)d_in[11];
  const float* lnf_w   = (const float*)d_in[12];
  const float* lnf_b   = (const float*)d_in[13];
  const float* head_w  = (const float*)d_in[14];

  char* ws = (char*)d_ws;
  long off = 0;
  auto alloc = [&](long bytes) { void* p = ws + off; off += (bytes + 1023) & ~1023L; return p; };
  float* h   = (float*)alloc((long)TOK * HID * 4);
  u16*   x   = (u16*)  alloc((long)TOK * HID * 2);
  u16*   qkv = (u16*)  alloc((long)TOK * QKV3 * 2);
  u16*   vT  = (u16*)  alloc(32L * HDIM * SEQ * 2);
  u16*   ctx = (u16*)  alloc((long)TOK * HID * 2);
  u16*   gu  = (u16*)  alloc((long)TOK * 2 * IPAD * 2);
  u16*   y   = (u16*)  alloc((long)TOK * IPAD * 2);
  u16*   whead = (u16*)alloc((long)VOCAB * HID * 2);   // 65.5 MB; layer weights alias inside
  u16* wq  = whead;                       // 3072*1024
  u16* wo  = wq + 3072 * 1024;            // 1024*1024
  u16* wgu = wo + 1024 * 1024;            // 5632*1024 (gate pad | up pad)
  u16* wd  = wgu + 5632 * 1024;           // 1024*2816
  u16* scores = (u16*)d_out;              // 32*1024*1024 bf16 = 67 MB scratch in d_out

  embed_kernel<<<TOK, 256, 0, stream>>>(ids, tok_emb, pos_emb, h);

  for (int l = 0; l < NLAYER; ++l) {
    ln_kernel<<<TOK, 256, 0, stream>>>(h, ln1_w + l * HID, ln1_b + l * HID, x);

    cvt_kernel<<<1536, 256, 0, stream>>>(qkv_w + (long)l * QKV3 * HID, wq, QKV3, HID, HID, 393216L);
    gemm_bt<128, 128, 0><<<dim3(16, 24, 1), 256, 0, stream>>>(
        x, wq, qkv, nullptr, HID, HID, QKV3, HID, 1.f, 1, 0, 0, 0, 0, 0, 0);

    vtrans_kernel<<<1024, 256, 0, stream>>>(qkv, vT);

    // scores[z][q][k] = 0.125 * Q.K^T   (z = b*16+h)
    gemm_bt<128, 128, 0><<<dim3(8, 8, 32), 256, 0, stream>>>(
        qkv, qkv + 1024, scores, nullptr, QKV3, QKV3, 1024, 64, 0.125f,
        16, (long)SEQ * QKV3, 64L, (long)SEQ * QKV3, 64L, 16L * 1048576L, 1048576L);

    softmax_kernel<<<8192, 256, 0, stream>>>(scores);

    // ctx[b][q][h*64+d] = P @ V
    gemm_bt<128, 64, 0><<<dim3(8, 1, 32), 256, 0, stream>>>(
        scores, vT, ctx, nullptr, 1024, 1024, HID, 1024, 1.f,
        16, 16L * 1048576L, 1048576L, 16L * 65536L, 65536L, 1048576L, 64L);

    cvt_kernel<<<512, 256, 0, stream>>>(o_w + (long)l * HID * HID, wo, HID, HID, HID, 131072L);
    gemm_bt<128, 128, 2><<<dim3(16, 8, 1), 256, 0, stream>>>(
        ctx, wo, h, h, HID, HID, HID, HID, 1.f, 1, 0, 0, 0, 0, 0, 0);

    ln_kernel<<<TOK, 256, 0, stream>>>(h, ln2_w + l * HID, ln2_b + l * HID, x);

    cvt_kernel<<<1408, 256, 0, stream>>>(gate_w + (long)l * INTER * HID, wgu, INTER, HID, HID, 360448L);
    cvt_kernel<<<1408, 256, 0, stream>>>(up_w + (long)l * INTER * HID, wgu + IPAD * HID, INTER, HID, HID, 360448L);
    gemm256<0><<<dim3(176), 512, 0, stream>>>(x, wgu, gu, 22, 2 * IPAD);

    silumul_kernel<<<2816, 256, 0, stream>>>(gu, y);

    cvt_kernel<<<1408, 256, 0, stream>>>(down_w + (long)l * HID * INTER, wd, HID, INTER, IPAD, 360448L);
    gemm_bt<128, 128, 2><<<dim3(16, 8, 1), 256, 0, stream>>>(
        y, wd, h, h, IPAD, IPAD, HID, IPAD, 1.f, 1, 0, 0, 0, 0, 0, 0);
  }

  ln_kernel<<<TOK, 256, 0, stream>>>(h, lnf_w, lnf_b, x);
  cvt_kernel<<<16000, 256, 0, stream>>>(head_w, whead, VOCAB, HID, HID, 4096000L);
  gemm256<1><<<dim3(1000), 512, 0, stream>>>(x, whead, d_out, 125, VOCAB);
}

// Round 2
// 1791.309 us; speedup vs baseline: 1.0383x; 1.0383x over previous
//
#include <hip/hip_runtime.h>

typedef unsigned short u16;
typedef __attribute__((ext_vector_type(8))) short bf16x8;   // 8 bf16 (4 VGPR) MFMA frag
typedef __attribute__((ext_vector_type(8))) unsigned short us8;
typedef __attribute__((ext_vector_type(4))) unsigned short us4;
typedef __attribute__((ext_vector_type(4))) float f32x4;

#define SEQ    1024
#define TOK    2048           // B*S
#define HID    1024
#define NLAYER 6
#define NHEAD  16
#define HDIM   64
#define QKV3   3072
#define INTER  2730
#define IPAD   2816
#define VOCAB  32000
#define LN_EPS 1e-5f

__device__ __forceinline__ u16 f2bf(float f) {
  unsigned u = __float_as_uint(f);
  return (u16)((u + 0x7fffu + ((u >> 16) & 1u)) >> 16);   // RNE
}
__device__ __forceinline__ float bf2f(u16 u) {
  return __uint_as_float(((unsigned)u) << 16);
}

__device__ __forceinline__ void gl_lds16(const void* g, void* l) {
  __builtin_amdgcn_global_load_lds(
      (const __attribute__((address_space(1))) void*)g,
      (__attribute__((address_space(3))) void*)l, 16, 0, 0);
}

// ---------------- embedding: h = tok_emb[id] + pos_emb[s] (f32) ----------------
__global__ __launch_bounds__(256) void embed_kernel(
    const int* __restrict__ ids, const float* __restrict__ tok,
    const float* __restrict__ pos, float* __restrict__ h)
{
  int t = blockIdx.x;
  int s = t & (SEQ - 1);
  int id = ids[t];
  int c = threadIdx.x * 4;
  float4 tv = *(const float4*)(tok + (long)id * HID + c);
  float4 pv = *(const float4*)(pos + (long)s * HID + c);
  float4 o;
  o.x = tv.x + pv.x; o.y = tv.y + pv.y; o.z = tv.z + pv.z; o.w = tv.w + pv.w;
  *(float4*)(h + (long)t * HID + c) = o;
}

// ---------------- layernorm: f32 in -> bf16 out ----------------
__global__ __launch_bounds__(256) void ln_kernel(
    const float* __restrict__ h, const float* __restrict__ w,
    const float* __restrict__ b, u16* __restrict__ out)
{
  int t = blockIdx.x;
  int tid = threadIdx.x;
  int lane = tid & 63, wid = tid >> 6;
  float4 v = *(const float4*)(h + (long)t * HID + tid * 4);
  float s1 = v.x + v.y + v.z + v.w;
  float s2 = v.x * v.x + v.y * v.y + v.z * v.z + v.w * v.w;
#pragma unroll
  for (int o = 32; o > 0; o >>= 1) { s1 += __shfl_down(s1, o); s2 += __shfl_down(s2, o); }
  __shared__ float r1[4], r2[4];
  if (lane == 0) { r1[wid] = s1; r2[wid] = s2; }
  __syncthreads();
  float t1 = r1[0] + r1[1] + r1[2] + r1[3];
  float t2 = r2[0] + r2[1] + r2[2] + r2[3];
  float mu = t1 * (1.f / HID);
  float var = t2 * (1.f / HID) - mu * mu;
  float rs = rsqrtf(var + LN_EPS);
  float4 wv = *(const float4*)(w + tid * 4);
  float4 bv = *(const float4*)(b + tid * 4);
  us4 o4;
  o4[0] = f2bf((v.x - mu) * rs * wv.x + bv.x);
  o4[1] = f2bf((v.y - mu) * rs * wv.y + bv.y);
  o4[2] = f2bf((v.z - mu) * rs * wv.z + bv.z);
  o4[3] = f2bf((v.w - mu) * rs * wv.w + bv.w);
  *(us4*)(out + (long)t * HID + tid * 4) = o4;
}

// ---------------- f32 -> bf16 weight convert with zero padding ----------------
__global__ __launch_bounds__(256) void cvt_kernel(
    const float* __restrict__ src, u16* __restrict__ dst,
    int N, int K, int Kpad, long total8)
{
  long i = (long)blockIdx.x * 256 + threadIdx.x;
  if (i >= total8) return;
  int kp8 = Kpad >> 3;
  int n = (int)(i / kp8);
  int kc = (int)(i % kp8);
  us8 o;
#pragma unroll
  for (int j = 0; j < 8; ++j) {
    int k = kc * 8 + j;
    float v = (n < N && k < K) ? src[(long)n * K + k] : 0.f;
    o[j] = f2bf(v);
  }
  *(us8*)(dst + i * 8) = o;
}

// ---------------- V transpose: vT[z][d][k] = qkv[b][k][2048 + h*64 + d] ----------------
__global__ __launch_bounds__(256) void vtrans_kernel(
    const u16* __restrict__ qkv, u16* __restrict__ vT)
{
  int gid = blockIdx.x * 256 + threadIdx.x;     // 32*64*128 total
  int d  = gid & 63;
  int kc = (gid >> 6) & 127;
  int z  = gid >> 13;                           // b*16+h
  int b = z >> 4, hh = z & 15;
  const u16* src = qkv + (long)b * SEQ * QKV3 + 2048 + hh * 64 + d;
  us8 v;
#pragma unroll
  for (int j = 0; j < 8; ++j) v[j] = src[(long)(kc * 8 + j) * QKV3];
  *(us8*)(vT + (long)z * 65536 + (long)d * 1024 + kc * 8) = v;
}

// ---------------- softmax in-place over bf16 rows of 1024 (one wave per row) ----------------
__global__ __launch_bounds__(256) void softmax_kernel(u16* __restrict__ sc)
{
  int row = blockIdx.x * 4 + (threadIdx.x >> 6);
  int lane = threadIdx.x & 63;
  u16* p = sc + (long)row * 1024 + lane * 16;
  us8 a = *(us8*)p;
  us8 b = *(us8*)(p + 8);
  float f[16];
#pragma unroll
  for (int j = 0; j < 8; ++j) { f[j] = bf2f(a[j]); f[8 + j] = bf2f(b[j]); }
  float m = f[0];
#pragma unroll
  for (int j = 1; j < 16; ++j) m = fmaxf(m, f[j]);
#pragma unroll
  for (int o = 1; o < 64; o <<= 1) m = fmaxf(m, __shfl_xor(m, o));
  float s = 0.f;
#pragma unroll
  for (int j = 0; j < 16; ++j) { f[j] = __expf(f[j] - m); s += f[j]; }
#pragma unroll
  for (int o = 1; o < 64; o <<= 1) s += __shfl_xor(s, o);
  float inv = 1.f / s;
#pragma unroll
  for (int j = 0; j < 8; ++j) { a[j] = f2bf(f[j] * inv); b[j] = f2bf(f[8 + j] * inv); }
  *(us8*)p = a;
  *(us8*)(p + 8) = b;
}

// ---------------- silu(gate)*up -> y (bf16) ----------------
__global__ __launch_bounds__(256) void silumul_kernel(
    const u16* __restrict__ gu, u16* __restrict__ y)
{
  long i = (long)blockIdx.x * 256 + threadIdx.x;   // TOK * IPAD/8
  int s = (int)(i / (IPAD / 8));
  int c8 = (int)(i % (IPAD / 8));
  const u16* base = gu + (long)s * (2 * IPAD) + c8 * 8;
  us8 g = *(const us8*)base;
  us8 u = *(const us8*)(base + IPAD);
  us8 o;
#pragma unroll
  for (int j = 0; j < 8; ++j) {
    float gf = bf2f(g[j]);
    float uf = bf2f(u[j]);
    float r = gf / (1.f + __expf(-gf)) * uf;
    o[j] = f2bf(r);
  }
  *(us8*)(y + i * 8) = o;
}

// ---------------- GEMM: C[m,n] = scale * sum_k A[m,k]*B[n,k] (+resid) ----------------
// A: [M][K] bf16 row-major (lda), B: [N][K] bf16 row-major (ldb).
// EPI: 0 = bf16 out (xscale), 1 = f32 out (xscale), 2 = f32 resid add.
// Batched via blockIdx.z: off = (z/bdiv)*s1 + (z%bdiv)*s2 per matrix.
template<int BM, int BN, int EPI>
__global__ __launch_bounds__(256) void gemm_bt(
    const u16* __restrict__ A, const u16* __restrict__ B,
    void* __restrict__ Cv, const float* __restrict__ resid,
    int lda, int ldb, int ldc, int K, float scale, int bdiv,
    long sA1, long sA2, long sB1, long sB2, long sC1, long sC2)
{
  constexpr int FM = BM / 32;   // frags per wave in M (wave tile = BM/2)
  constexpr int FN = BN / 32;
  __shared__ u16 As[2][BM * 32];
  __shared__ u16 Bs[2][BN * 32];

  const int tid = threadIdx.x;
  const int lane = tid & 63;
  const int wid = tid >> 6;
  const int wm = wid >> 1, wn = wid & 1;

  const int z = blockIdx.z;
  const long offA = (long)(z / bdiv) * sA1 + (long)(z % bdiv) * sA2;
  const long offB = (long)(z / bdiv) * sB1 + (long)(z % bdiv) * sB2;
  const long offC = (long)(z / bdiv) * sC1 + (long)(z % bdiv) * sC2;

  const u16* Ab = A + offA + (long)blockIdx.x * BM * lda;
  const u16* Bb = B + offB + (long)blockIdx.y * BN * ldb;

  auto stage = [&](int buf, int kt) {
    const u16* a = Ab + (long)kt * 32;
    const u16* bsrc = Bb + (long)kt * 32;
#pragma unroll
    for (int i = 0; i < BM / 64; ++i) {
      int row = i * 64 + wid * 16 + (lane >> 2);
      gl_lds16(a + (long)row * lda + (lane & 3) * 8, &As[buf][i * 2048 + wid * 512]);
    }
#pragma unroll
    for (int i = 0; i < BN / 64; ++i) {
      int row = i * 64 + wid * 16 + (lane >> 2);
      gl_lds16(bsrc + (long)row * ldb + (lane & 3) * 8, &Bs[buf][i * 2048 + wid * 512]);
    }
  };

  f32x4 acc[FM][FN];
#pragma unroll
  for (int i = 0; i < FM; ++i)
#pragma unroll
    for (int j = 0; j < FN; ++j) acc[i][j] = (f32x4){0.f, 0.f, 0.f, 0.f};

  int aoff[FM], boff[FN];
#pragma unroll
  for (int i = 0; i < FM; ++i)
    aoff[i] = (wm * (BM / 2) + i * 16 + (lane & 15)) * 32 + (lane >> 4) * 8;
#pragma unroll
  for (int j = 0; j < FN; ++j)
    boff[j] = (wn * (BN / 2) + j * 16 + (lane & 15)) * 32 + (lane >> 4) * 8;

  const int KT = K >> 5;
  stage(0, 0);
  __syncthreads();
  int cur = 0;
  for (int kt = 0; kt < KT; ++kt) {
    if (kt + 1 < KT) stage(cur ^ 1, kt + 1);
    bf16x8 av[FM], bv[FN];
#pragma unroll
    for (int i = 0; i < FM; ++i) av[i] = *(const bf16x8*)&As[cur][aoff[i]];
#pragma unroll
    for (int j = 0; j < FN; ++j) bv[j] = *(const bf16x8*)&Bs[cur][boff[j]];
#pragma unroll
    for (int i = 0; i < FM; ++i)
#pragma unroll
      for (int j = 0; j < FN; ++j)
        acc[i][j] = __builtin_amdgcn_mfma_f32_16x16x32_bf16(av[i], bv[j], acc[i][j], 0, 0, 0);
    __syncthreads();
    cur ^= 1;
  }

  const int r0 = blockIdx.x * BM + wm * (BM / 2) + (lane >> 4) * 4;
  const int c0 = blockIdx.y * BN + wn * (BN / 2) + (lane & 15);
#pragma unroll
  for (int i = 0; i < FM; ++i) {
#pragma unroll
    for (int j = 0; j < FN; ++j) {
      f32x4 v = acc[i][j];
#pragma unroll
      for (int r = 0; r < 4; ++r) {
        long idx = offC + (long)(r0 + i * 16 + r) * ldc + (c0 + j * 16);
        if (EPI == 0)       ((u16*)Cv)[idx] = f2bf(v[r] * scale);
        else if (EPI == 1)  ((float*)Cv)[idx] = v[r] * scale;
        else                ((float*)Cv)[idx] = resid[idx] + v[r];
      }
    }
  }
}

// ---------------- gemm256: 256x256 tile, BK=64, 8-phase m201-style schedule ----------------
// C[m,n] = sum_k A[m,k]*B[n,k].  A:[2048][1024] bf16, B:[256*NB][1024] bf16, K=1024.
// 512 thr = 8 waves (2M x 4N), wave tile 128x64. Iter = 2 K-tiles (dbuf0/dbuf1),
// 8 phases/iter, 16 MFMA/phase (one 64x32 wave-quadrant x K=64).
// LDS 128 KiB: [dbuf][A|B][half][kgroup 8][row 128][8 bf16]; K-major -> 16
// consecutive lanes read 256 contiguous bytes (0 bank conflicts, measured r1).
// Staging: 1 half-tile (2 x gl_lds16/thread) per phase; ledger: 12 loads in
// flight, vmcnt(4) at end of phases 4/8 only (never 0 in steady state).
// Every LDS slot overwrite is >= 1 full barrier after its last reader, whose
// reads retire before that barrier (compiler lgkmcnt precedes the MFMA).
template<int EPI>
__global__ __launch_bounds__(512, 1) void gemm256(
    const u16* __restrict__ A, const u16* __restrict__ B,
    void* __restrict__ Cv, int NB, int ldc)
{
  __shared__ u16 lds[2][2][2][8][128][8];   // [dbuf][mat][half][kg][row][8] = 128 KiB

  const int tid  = threadIdx.x;
  const int lane = tid & 63;
  const int w    = tid >> 6;           // 0..7
  const int wm   = w >> 2;             // 0..1  (M half of block)
  const int wn   = w & 3;              // 0..3  (N quarter of block)
  const int arow = lane & 15;
  const int kg   = lane >> 4;          // 0..3

  const int flat = blockIdx.x;                     // 0 .. 8*NB-1
  const int swz  = (flat & 7) * NB + (flat >> 3);  // bijective (nwg % 8 == 0)
  const int bm   = swz & 7;
  const int bn   = swz >> 3;

  const u16* Ab = A + (long)bm * 256 * 1024;
  const u16* Bb = B + (long)bn * 256 * 1024;

  // stage one half-tile (128 rows x 64 k) of K-tile t: 2 gl_lds16/thread.
  // unit u = w*2+i: kgroup g=u&7, rowgroup rg=u>>3. LDS dest wave-uniform,
  // HW adds lane*16 -> row rg*64+lane of kgroup g. Global src per-lane row.
  auto stage = [&](int mat, int d, int half, int t) {
#pragma unroll
    for (int i = 0; i < 2; ++i) {
      const int u  = w * 2 + i;
      const int g  = u & 7;
      const int rg = u >> 3;
      const u16* src = (mat == 0 ? Ab : Bb)
                     + (long)(half * 128 + rg * 64 + lane) * 1024 + t * 64 + g * 8;
      gl_lds16(src, &lds[d][mat][half][g][rg * 64][0]);
    }
  };

  f32x4 acc[2][2][4][2];   // [qm][qn][f][n]
#pragma unroll
  for (int qm = 0; qm < 2; ++qm)
#pragma unroll
    for (int qn = 0; qn < 2; ++qn)
#pragma unroll
      for (int f = 0; f < 4; ++f)
#pragma unroll
        for (int n = 0; n < 2; ++n) acc[qm][qn][f][n] = (f32x4){0.f, 0.f, 0.f, 0.f};

  bf16x8 a[4][2];      // A frags of current m-quadrant  [f][ks]
  bf16x8 b[2][2][2];   // B frags of both n-quadrants    [qn][n][ks]

  auto rdA = [&](int d, int qm) {   // 8 ds_read_b128
#pragma unroll
    for (int f = 0; f < 4; ++f)
#pragma unroll
      for (int ks = 0; ks < 2; ++ks)
        a[f][ks] = *(const bf16x8*)&lds[d][0][wm][ks * 4 + kg][qm * 64 + f * 16 + arow][0];
  };
  auto rdB = [&](int d, int qn) {   // 4 ds_read_b128
#pragma unroll
    for (int n = 0; n < 2; ++n)
#pragma unroll
      for (int ks = 0; ks < 2; ++ks)
        b[qn][n][ks] = *(const bf16x8*)&lds[d][1][wn >> 1][ks * 4 + kg]
                                          [(wn & 1) * 64 + qn * 32 + n * 16 + arow][0];
  };
  auto mm = [&](int qm, int qn) {   // 16 MFMA, K ascending (ks inner)
    __builtin_amdgcn_s_setprio(1);
#pragma unroll
    for (int f = 0; f < 4; ++f)
#pragma unroll
      for (int n = 0; n < 2; ++n)
#pragma unroll
        for (int ks = 0; ks < 2; ++ks)
          acc[qm][qn][f][n] = __builtin_amdgcn_mfma_f32_16x16x32_bf16(
              a[f][ks], b[qn][n][ks], acc[qm][qn][f][n], 0, 0, 0);
    __builtin_amdgcn_s_setprio(0);
  };

#define BAR asm volatile("s_barrier" ::: "memory")

  // prologue: tile0 (all 4 halves) + tile1 A0/B0; drain tile0, keep 2 stages.
  stage(1, 0, 0, 0);   // B0(0)
  stage(0, 0, 0, 0);   // A0(0)
  stage(0, 0, 1, 0);   // A1(0)
  stage(1, 0, 1, 0);   // B1(0)
  stage(1, 1, 0, 1);   // B0(1)
  stage(0, 1, 0, 1);   // A0(1)
  asm volatile("s_waitcnt vmcnt(4)" ::: "memory");
  BAR;

  const int iters = 8;   // K=1024, BK=64, 2 K-tiles per iter
#pragma unroll 1
  for (int it = 0; it < iters; ++it) {
    const int T = 2 * it;
    const bool pf = (it + 1 < iters);
    // ---- p0: tile T (dbuf0), quadrant (0,0) ----
    rdA(0, 0); rdB(0, 0);
    stage(0, 1, 1, T + 1);                 // A1(T+1) -> dbuf1
    BAR; mm(0, 0); BAR;
    // ---- p1: quadrant (0,1) ----
    rdB(0, 1);
    stage(1, 1, 1, T + 1);                 // B1(T+1) -> dbuf1
    BAR; mm(0, 1); BAR;
    // ---- p2: quadrant (1,0) ----
    rdA(0, 1);
    if (pf) stage(1, 0, 0, T + 2);         // B0(T+2) -> dbuf0
    BAR; mm(1, 0); BAR;
    // ---- p3: quadrant (1,1); K-tile boundary drain ----
    if (pf) stage(0, 0, 0, T + 2);         // A0(T+2) -> dbuf0
    BAR; mm(1, 1);
    if (pf) asm volatile("s_waitcnt vmcnt(4)" ::: "memory");
    else    asm volatile("s_waitcnt vmcnt(0)" ::: "memory");
    BAR;
    // ---- p4: tile T+1 (dbuf1), quadrant (0,0) ----
    rdA(1, 0); rdB(1, 0);
    if (pf) stage(0, 0, 1, T + 2);         // A1(T+2) -> dbuf0
    BAR; mm(0, 0); BAR;
    // ---- p5: quadrant (0,1) ----
    rdB(1, 1);
    if (pf) stage(1, 0, 1, T + 2);         // B1(T+2) -> dbuf0
    BAR; mm(0, 1); BAR;
    // ---- p6: quadrant (1,0) ----
    rdA(1, 1);
    if (pf) stage(1, 1, 0, T + 3);         // B0(T+3) -> dbuf1
    BAR; mm(1, 0); BAR;
    // ---- p7: quadrant (1,1); K-tile boundary drain ----
    if (pf) stage(0, 1, 0, T + 3);         // A0(T+3) -> dbuf1
    BAR; mm(1, 1);
    if (pf) asm volatile("s_waitcnt vmcnt(4)" ::: "memory");
    BAR;
  }
#undef BAR

  // epilogue: C row = (lane>>4)*4 + reg, col = lane&15 (m89-verified layout)
#pragma unroll
  for (int qm = 0; qm < 2; ++qm) {
#pragma unroll
    for (int qn = 0; qn < 2; ++qn) {
#pragma unroll
      for (int f = 0; f < 4; ++f) {
        const int r0 = bm * 256 + wm * 128 + qm * 64 + f * 16 + kg * 4;
#pragma unroll
        for (int n = 0; n < 2; ++n) {
          const int c = bn * 256 + wn * 64 + qn * 32 + n * 16 + arow;
          f32x4 v = acc[qm][qn][f][n];
#pragma unroll
          for (int r = 0; r < 4; ++r) {
            long idx = (long)(r0 + r) * ldc + c;
            if (EPI == 0) ((u16*)Cv)[idx] = f2bf(v[r]);
            else          ((float*)Cv)[idx] = v[r];
          }
        }
      }
    }
  }
}

extern "C" void kernel_launch(void* const* d_in, const int* in_sizes, int n_in,
                              void* d_out, int out_size, void* d_ws, size_t ws_size,
                              hipStream_t stream)
{
  (void)in_sizes; (void)n_in; (void)out_size; (void)ws_size;
  const int*   ids     = (const int*)d_in[0];
  const float* tok_emb = (const float*)d_in[1];
  const float* pos_emb = (const float*)d_in[2];
  const float* qkv_w   = (const float*)d_in[3];
  const float* o_w     = (const float*)d_in[4];
  const float* gate_w  = (const float*)d_in[5];
  const float* up_w    = (const float*)d_in[6];
  const float* down_w  = (const float*)d_in[7];
  const float* ln1_w   = (const float*)d_in[8];
  const float* ln1_b   = (const float*)d_in[9];
  const float* ln2_w   = (const float*)d_in[10];
  const float* ln2_b   = (const float*)d_in[11];
  const float* lnf_w   = (const float*)d_in[12];
  const float* lnf_b   = (const float*)d_in[13];
  const float* head_w  = (const float*)d_in[14];

  char* ws = (char*)d_ws;
  long off = 0;
  auto alloc = [&](long bytes) { void* p = ws + off; off += (bytes + 1023) & ~1023L; return p; };
  float* h   = (float*)alloc((long)TOK * HID * 4);
  u16*   x   = (u16*)  alloc((long)TOK * HID * 2);
  u16*   qkv = (u16*)  alloc((long)TOK * QKV3 * 2);
  u16*   vT  = (u16*)  alloc(32L * HDIM * SEQ * 2);
  u16*   ctx = (u16*)  alloc((long)TOK * HID * 2);
  u16*   gu  = (u16*)  alloc((long)TOK * 2 * IPAD * 2);
  u16*   y   = (u16*)  alloc((long)TOK * IPAD * 2);
  u16*   whead = (u16*)alloc((long)VOCAB * HID * 2);   // 65.5 MB; layer weights alias inside
  u16* wq  = whead;                       // 3072*1024
  u16* wo  = wq + 3072 * 1024;            // 1024*1024
  u16* wgu = wo + 1024 * 1024;            // 5632*1024 (gate pad | up pad)
  u16* wd  = wgu + 5632 * 1024;           // 1024*2816
  u16* scores = (u16*)d_out;              // 32*1024*1024 bf16 = 67 MB scratch in d_out

  embed_kernel<<<TOK, 256, 0, stream>>>(ids, tok_emb, pos_emb, h);

  for (int l = 0; l < NLAYER; ++l) {
    ln_kernel<<<TOK, 256, 0, stream>>>(h, ln1_w + l * HID, ln1_b + l * HID, x);

    cvt_kernel<<<1536, 256, 0, stream>>>(qkv_w + (long)l * QKV3 * HID, wq, QKV3, HID, HID, 393216L);
    gemm_bt<128, 128, 0><<<dim3(16, 24, 1), 256, 0, stream>>>(
        x, wq, qkv, nullptr, HID, HID, QKV3, HID, 1.f, 1, 0, 0, 0, 0, 0, 0);

    vtrans_kernel<<<1024, 256, 0, stream>>>(qkv, vT);

    // scores[z][q][k] = 0.125 * Q.K^T   (z = b*16+h)
    gemm_bt<128, 128, 0><<<dim3(8, 8, 32), 256, 0, stream>>>(
        qkv, qkv + 1024, scores, nullptr, QKV3, QKV3, 1024, 64, 0.125f,
        16, (long)SEQ * QKV3, 64L, (long)SEQ * QKV3, 64L, 16L * 1048576L, 1048576L);

    softmax_kernel<<<8192, 256, 0, stream>>>(scores);

    // ctx[b][q][h*64+d] = P @ V
    gemm_bt<128, 64, 0><<<dim3(8, 1, 32), 256, 0, stream>>>(
        scores, vT, ctx, nullptr, 1024, 1024, HID, 1024, 1.f,
        16, 16L * 1048576L, 1048576L, 16L * 65536L, 65536L, 1048576L, 64L);

    cvt_kernel<<<512, 256, 0, stream>>>(o_w + (long)l * HID * HID, wo, HID, HID, HID, 131072L);
    gemm_bt<128, 128, 2><<<dim3(16, 8, 1), 256, 0, stream>>>(
        ctx, wo, h, h, HID, HID, HID, HID, 1.f, 1, 0, 0, 0, 0, 0, 0);

    ln_kernel<<<TOK, 256, 0, stream>>>(h, ln2_w + l * HID, ln2_b + l * HID, x);

    cvt_kernel<<<1408, 256, 0, stream>>>(gate_w + (long)l * INTER * HID, wgu, INTER, HID, HID, 360448L);
    cvt_kernel<<<1408, 256, 0, stream>>>(up_w + (long)l * INTER * HID, wgu + IPAD * HID, INTER, HID, HID, 360448L);
    gemm_bt<128, 128, 0><<<dim3(16, 44, 1), 256, 0, stream>>>(
        x, wgu, gu, nullptr, HID, HID, 2 * IPAD, HID, 1.f, 1, 0, 0, 0, 0, 0, 0);

    silumul_kernel<<<2816, 256, 0, stream>>>(gu, y);

    cvt_kernel<<<1408, 256, 0, stream>>>(down_w + (long)l * HID * INTER, wd, HID, INTER, IPAD, 360448L);
    gemm_bt<128, 128, 2><<<dim3(16, 8, 1), 256, 0, stream>>>(
        y, wd, h, h, IPAD, IPAD, HID, IPAD, 1.f, 1, 0, 0, 0, 0, 0, 0);
  }

  ln_kernel<<<TOK, 256, 0, stream>>>(h, lnf_w, lnf_b, x);
  cvt_kernel<<<16000, 256, 0, stream>>>(head_w, whead, VOCAB, HID, HID, 4096000L);
  gemm256<1><<<dim3(1000), 512, 0, stream>>>(x, whead, d_out, 125, VOCAB);
}

// Round 3
// 1646.907 us; speedup vs baseline: 1.1294x; 1.0877x over previous
//
#include <hip/hip_runtime.h>

typedef unsigned short u16;
typedef __attribute__((ext_vector_type(8))) short bf16x8;   // 8 bf16 (4 VGPR) MFMA frag
typedef __attribute__((ext_vector_type(8))) unsigned short us8;
typedef __attribute__((ext_vector_type(4))) unsigned short us4;
typedef __attribute__((ext_vector_type(4))) float f32x4;

#define SEQ    1024
#define TOK    2048           // B*S
#define HID    1024
#define NLAYER 6
#define NHEAD  16
#define HDIM   64
#define QKV3   3072
#define INTER  2730
#define IPAD   2816
#define VOCAB  32000
#define LN_EPS 1e-5f

__device__ __forceinline__ u16 f2bf(float f) {
  unsigned u = __float_as_uint(f);
  return (u16)((u + 0x7fffu + ((u >> 16) & 1u)) >> 16);   // RNE
}
__device__ __forceinline__ float bf2f(u16 u) {
  return __uint_as_float(((unsigned)u) << 16);
}

__device__ __forceinline__ void gl_lds16(const void* g, void* l) {
  __builtin_amdgcn_global_load_lds(
      (const __attribute__((address_space(1))) void*)g,
      (__attribute__((address_space(3))) void*)l, 16, 0, 0);
}

// ---------------- embedding: h = tok_emb[id] + pos_emb[s] (f32) ----------------
__global__ __launch_bounds__(256) void embed_kernel(
    const int* __restrict__ ids, const float* __restrict__ tok,
    const float* __restrict__ pos, float* __restrict__ h)
{
  int t = blockIdx.x;
  int s = t & (SEQ - 1);
  int id = ids[t];
  int c = threadIdx.x * 4;
  float4 tv = *(const float4*)(tok + (long)id * HID + c);
  float4 pv = *(const float4*)(pos + (long)s * HID + c);
  float4 o;
  o.x = tv.x + pv.x; o.y = tv.y + pv.y; o.z = tv.z + pv.z; o.w = tv.w + pv.w;
  *(float4*)(h + (long)t * HID + c) = o;
}

// ---------------- layernorm: f32 in -> bf16 out ----------------
__global__ __launch_bounds__(256) void ln_kernel(
    const float* __restrict__ h, const float* __restrict__ w,
    const float* __restrict__ b, u16* __restrict__ out)
{
  int t = blockIdx.x;
  int tid = threadIdx.x;
  int lane = tid & 63, wid = tid >> 6;
  float4 v = *(const float4*)(h + (long)t * HID + tid * 4);
  float s1 = v.x + v.y + v.z + v.w;
  float s2 = v.x * v.x + v.y * v.y + v.z * v.z + v.w * v.w;
#pragma unroll
  for (int o = 32; o > 0; o >>= 1) { s1 += __shfl_down(s1, o); s2 += __shfl_down(s2, o); }
  __shared__ float r1[4], r2[4];
  if (lane == 0) { r1[wid] = s1; r2[wid] = s2; }
  __syncthreads();
  float t1 = r1[0] + r1[1] + r1[2] + r1[3];
  float t2 = r2[0] + r2[1] + r2[2] + r2[3];
  float mu = t1 * (1.f / HID);
  float var = t2 * (1.f / HID) - mu * mu;
  float rs = rsqrtf(var + LN_EPS);
  float4 wv = *(const float4*)(w + tid * 4);
  float4 bv = *(const float4*)(b + tid * 4);
  us4 o4;
  o4[0] = f2bf((v.x - mu) * rs * wv.x + bv.x);
  o4[1] = f2bf((v.y - mu) * rs * wv.y + bv.y);
  o4[2] = f2bf((v.z - mu) * rs * wv.z + bv.z);
  o4[3] = f2bf((v.w - mu) * rs * wv.w + bv.w);
  *(us4*)(out + (long)t * HID + tid * 4) = o4;
}

// ---------------- f32 -> bf16 weight convert with zero padding ----------------
// src is [N][K] row-major; dst is [Npad][Kpad]; i enumerates Npad*Kpad/8 chunks
__global__ __launch_bounds__(256) void cvt_kernel(
    const float* __restrict__ src, u16* __restrict__ dst,
    int N, int K, int Kpad, long total8)
{
  long i = (long)blockIdx.x * 256 + threadIdx.x;
  if (i >= total8) return;
  int kp8 = Kpad >> 3;
  int n = (int)(i / kp8);
  int kc = (int)(i % kp8);
  us8 o;
#pragma unroll
  for (int j = 0; j < 8; ++j) {
    int k = kc * 8 + j;
    float v = (n < N && k < K) ? src[(long)n * K + k] : 0.f;
    o[j] = f2bf(v);
  }
  *(us8*)(dst + i * 8) = o;
}

// -------- interleaved gate/up convert: dst row 2g = gate[g], 2g+1 = up[g] --------
// dst [5632][1024] bf16; zero-pad rows with g >= INTER.
__global__ __launch_bounds__(256) void cvt2i_kernel(
    const float* __restrict__ gate, const float* __restrict__ up,
    u16* __restrict__ dst, long total8)
{
  long i = (long)blockIdx.x * 256 + threadIdx.x;   // 5632*128
  if (i >= total8) return;
  int n  = (int)(i >> 7);        // interleaved row 0..5631
  int kc = (int)(i & 127);
  int g  = n >> 1;
  const float* src = (n & 1) ? up : gate;
  us8 o;
#pragma unroll
  for (int j = 0; j < 8; ++j) {
    int k = kc * 8 + j;
    float v = (g < INTER) ? src[(long)g * HID + k] : 0.f;
    o[j] = f2bf(v);
  }
  *(us8*)(dst + i * 8) = o;
}

// ---------------- V transpose: vT[z][d][k] = qkv[b][k][2048 + h*64 + d] ----------------
__global__ __launch_bounds__(256) void vtrans_kernel(
    const u16* __restrict__ qkv, u16* __restrict__ vT)
{
  int gid = blockIdx.x * 256 + threadIdx.x;     // 32*64*128 total
  int d  = gid & 63;
  int kc = (gid >> 6) & 127;
  int z  = gid >> 13;                           // b*16+h
  int b = z >> 4, hh = z & 15;
  const u16* src = qkv + (long)b * SEQ * QKV3 + 2048 + hh * 64 + d;
  us8 v;
#pragma unroll
  for (int j = 0; j < 8; ++j) v[j] = src[(long)(kc * 8 + j) * QKV3];
  *(us8*)(vT + (long)z * 65536 + (long)d * 1024 + kc * 8) = v;
}

// ---------------- softmax in-place over bf16 rows of 1024 (one wave per row) ----------------
__global__ __launch_bounds__(256) void softmax_kernel(u16* __restrict__ sc)
{
  int row = blockIdx.x * 4 + (threadIdx.x >> 6);
  int lane = threadIdx.x & 63;
  u16* p = sc + (long)row * 1024 + lane * 16;
  us8 a = *(us8*)p;
  us8 b = *(us8*)(p + 8);
  float f[16];
#pragma unroll
  for (int j = 0; j < 8; ++j) { f[j] = bf2f(a[j]); f[8 + j] = bf2f(b[j]); }
  float m = f[0];
#pragma unroll
  for (int j = 1; j < 16; ++j) m = fmaxf(m, f[j]);
#pragma unroll
  for (int o = 1; o < 64; o <<= 1) m = fmaxf(m, __shfl_xor(m, o));
  float s = 0.f;
#pragma unroll
  for (int j = 0; j < 16; ++j) { f[j] = __expf(f[j] - m); s += f[j]; }
#pragma unroll
  for (int o = 1; o < 64; o <<= 1) s += __shfl_xor(s, o);
  float inv = 1.f / s;
#pragma unroll
  for (int j = 0; j < 8; ++j) { a[j] = f2bf(f[j] * inv); b[j] = f2bf(f[8 + j] * inv); }
  *(us8*)p = a;
  *(us8*)(p + 8) = b;
}

// ---------------- GEMM: C[m,n] = scale * sum_k A[m,k]*B[n,k] (+resid) ----------------
// A: [M][K] bf16 row-major (lda), B: [N][K] bf16 row-major (ldb).
// EPI: 0 = bf16 out (xscale), 1 = f32 out (xscale), 2 = f32 resid add,
//      3 = fused silu: B rows interleaved (even=gate,up=odd); even lanes write
//          y[row][c>>1] = silu(gate)*up via __shfl_xor(v,1).  ldc = IPAD.
// Batched via blockIdx.z: off = (z/bdiv)*s1 + (z%bdiv)*s2 per matrix.
template<int BM, int BN, int EPI>
__global__ __launch_bounds__(256) void gemm_bt(
    const u16* __restrict__ A, const u16* __restrict__ B,
    void* __restrict__ Cv, const float* __restrict__ resid,
    int lda, int ldb, int ldc, int K, float scale, int bdiv,
    long sA1, long sA2, long sB1, long sB2, long sC1, long sC2)
{
  constexpr int FM = BM / 32;   // frags per wave in M (wave tile = BM/2)
  constexpr int FN = BN / 32;
  __shared__ u16 As[2][BM * 32];
  __shared__ u16 Bs[2][BN * 32];

  const int tid = threadIdx.x;
  const int lane = tid & 63;
  const int wid = tid >> 6;
  const int wm = wid >> 1, wn = wid & 1;

  const int z = blockIdx.z;
  const long offA = (long)(z / bdiv) * sA1 + (long)(z % bdiv) * sA2;
  const long offB = (long)(z / bdiv) * sB1 + (long)(z % bdiv) * sB2;
  const long offC = (long)(z / bdiv) * sC1 + (long)(z % bdiv) * sC2;

  const u16* Ab = A + offA + (long)blockIdx.x * BM * lda;
  const u16* Bb = B + offB + (long)blockIdx.y * BN * ldb;

  auto stage = [&](int buf, int kt) {
    const u16* a = Ab + (long)kt * 32;
    const u16* bsrc = Bb + (long)kt * 32;
#pragma unroll
    for (int i = 0; i < BM / 64; ++i) {
      int row = i * 64 + wid * 16 + (lane >> 2);
      gl_lds16(a + (long)row * lda + (lane & 3) * 8, &As[buf][i * 2048 + wid * 512]);
    }
#pragma unroll
    for (int i = 0; i < BN / 64; ++i) {
      int row = i * 64 + wid * 16 + (lane >> 2);
      gl_lds16(bsrc + (long)row * ldb + (lane & 3) * 8, &Bs[buf][i * 2048 + wid * 512]);
    }
  };

  f32x4 acc[FM][FN];
#pragma unroll
  for (int i = 0; i < FM; ++i)
#pragma unroll
    for (int j = 0; j < FN; ++j) acc[i][j] = (f32x4){0.f, 0.f, 0.f, 0.f};

  int aoff[FM], boff[FN];
#pragma unroll
  for (int i = 0; i < FM; ++i)
    aoff[i] = (wm * (BM / 2) + i * 16 + (lane & 15)) * 32 + (lane >> 4) * 8;
#pragma unroll
  for (int j = 0; j < FN; ++j)
    boff[j] = (wn * (BN / 2) + j * 16 + (lane & 15)) * 32 + (lane >> 4) * 8;

  const int KT = K >> 5;
  stage(0, 0);
  __syncthreads();
  int cur = 0;
  for (int kt = 0; kt < KT; ++kt) {
    if (kt + 1 < KT) stage(cur ^ 1, kt + 1);
    bf16x8 av[FM], bv[FN];
#pragma unroll
    for (int i = 0; i < FM; ++i) av[i] = *(const bf16x8*)&As[cur][aoff[i]];
#pragma unroll
    for (int j = 0; j < FN; ++j) bv[j] = *(const bf16x8*)&Bs[cur][boff[j]];
#pragma unroll
    for (int i = 0; i < FM; ++i)
#pragma unroll
      for (int j = 0; j < FN; ++j)
        acc[i][j] = __builtin_amdgcn_mfma_f32_16x16x32_bf16(av[i], bv[j], acc[i][j], 0, 0, 0);
    __syncthreads();
    cur ^= 1;
  }

  const int r0 = blockIdx.x * BM + wm * (BM / 2) + (lane >> 4) * 4;
  const int c0 = blockIdx.y * BN + wn * (BN / 2) + (lane & 15);
#pragma unroll
  for (int i = 0; i < FM; ++i) {
#pragma unroll
    for (int j = 0; j < FN; ++j) {
      f32x4 v = acc[i][j];
#pragma unroll
      for (int r = 0; r < 4; ++r) {
        if (EPI == 3) {
          float pv = __shfl_xor(v[r], 1);          // partner col (up for even lanes)
          if ((lane & 1) == 0) {
            float gf = v[r];
            float res = gf / (1.f + __expf(-gf)) * pv;
            int cc = c0 + j * 16;                  // even (gate) column
            long idx = offC + (long)(r0 + i * 16 + r) * ldc + (cc >> 1);
            ((u16*)Cv)[idx] = f2bf(res);
          }
        } else {
          long idx = offC + (long)(r0 + i * 16 + r) * ldc + (c0 + j * 16);
          if (EPI == 0)       ((u16*)Cv)[idx] = f2bf(v[r] * scale);
          else if (EPI == 1)  ((float*)Cv)[idx] = v[r] * scale;
          else                ((float*)Cv)[idx] = resid[idx] + v[r];
        }
      }
    }
  }
}

// ---------------- gemm256: 256x256 tile, BK=64, 4 merged phases/iter ----------------
// C[m,n] = sum_k A[m,k]*B[n,k].  A:[2048][1024] bf16, B:[256*NB][1024] bf16, K=1024.
// 512 thr = 8 waves (2M x 4N), wave tile 128x64. Iter = 2 K-tiles (dbuf0/dbuf1),
// 4 phases/iter, 32 MFMA per barrier interval (one 64x64 wave-half x K=64).
// LDS 128 KiB: [dbuf][A|B][half][kgroup 8][row 128][8 bf16]; K-major, 0 conflicts
// (measured r1/r2).  Staging: 2 half-tiles per phase; ledger: 12 loads in flight
// max, vmcnt(4) at K-tile boundaries only (never 0 in steady state).  Every LDS
// slot overwrite is >= 1 full barrier after its last reader.
template<int EPI>
__global__ __launch_bounds__(512, 1) void gemm256(
    const u16* __restrict__ A, const u16* __restrict__ B,
    void* __restrict__ Cv, int NB, int ldc)
{
  __shared__ u16 lds[2][2][2][8][128][8];   // [dbuf][mat][half][kg][row][8] = 128 KiB

  const int tid  = threadIdx.x;
  const int lane = tid & 63;
  const int w    = tid >> 6;           // 0..7
  const int wm   = w >> 2;             // 0..1  (M half of block)
  const int wn   = w & 3;              // 0..3  (N quarter of block)
  const int arow = lane & 15;
  const int kg   = lane >> 4;          // 0..3

  const int flat = blockIdx.x;                     // 0 .. 8*NB-1
  const int swz  = (flat & 7) * NB + (flat >> 3);  // bijective (nwg % 8 == 0)
  const int bm   = swz & 7;
  const int bn   = swz >> 3;

  const u16* Ab = A + (long)bm * 256 * 1024;
  const u16* Bb = B + (long)bn * 256 * 1024;

  // stage one half-tile (128 rows x 64 k) of K-tile t: 2 gl_lds16/thread.
  auto stage = [&](int mat, int d, int half, int t) {
#pragma unroll
    for (int i = 0; i < 2; ++i) {
      const int u  = w * 2 + i;
      const int g  = u & 7;
      const int rg = u >> 3;
      const u16* src = (mat == 0 ? Ab : Bb)
                     + (long)(half * 128 + rg * 64 + lane) * 1024 + t * 64 + g * 8;
      gl_lds16(src, &lds[d][mat][half][g][rg * 64][0]);
    }
  };

  f32x4 acc[2][2][4][2];   // [qm][qn][f][n]
#pragma unroll
  for (int qm = 0; qm < 2; ++qm)
#pragma unroll
    for (int qn = 0; qn < 2; ++qn)
#pragma unroll
      for (int f = 0; f < 4; ++f)
#pragma unroll
        for (int n = 0; n < 2; ++n) acc[qm][qn][f][n] = (f32x4){0.f, 0.f, 0.f, 0.f};

  bf16x8 a[4][2];      // A frags of current m-quadrant  [f][ks]
  bf16x8 b[2][2][2];   // B frags of both n-quadrants    [qn][n][ks]

  auto rdA = [&](int d, int qm) {   // 8 ds_read_b128
#pragma unroll
    for (int f = 0; f < 4; ++f)
#pragma unroll
      for (int ks = 0; ks < 2; ++ks)
        a[f][ks] = *(const bf16x8*)&lds[d][0][wm][ks * 4 + kg][qm * 64 + f * 16 + arow][0];
  };
  auto rdB = [&](int d, int qn) {   // 4 ds_read_b128
#pragma unroll
    for (int n = 0; n < 2; ++n)
#pragma unroll
      for (int ks = 0; ks < 2; ++ks)
        b[qn][n][ks] = *(const bf16x8*)&lds[d][1][wn >> 1][ks * 4 + kg]
                                          [(wn & 1) * 64 + qn * 32 + n * 16 + arow][0];
  };
  auto mm = [&](int qm, int qn) {   // 16 MFMA
#pragma unroll
    for (int f = 0; f < 4; ++f)
#pragma unroll
      for (int n = 0; n < 2; ++n)
#pragma unroll
        for (int ks = 0; ks < 2; ++ks)
          acc[qm][qn][f][n] = __builtin_amdgcn_mfma_f32_16x16x32_bf16(
              a[f][ks], b[qn][n][ks], acc[qm][qn][f][n], 0, 0, 0);
  };

#define BAR asm volatile("s_barrier" ::: "memory")
#define PRIO1 __builtin_amdgcn_s_setprio(1)
#define PRIO0 __builtin_amdgcn_s_setprio(0)

  // prologue: tile0 (all 4 halves) + tile1 A0/B0; drain tile0, keep 2 stages.
  stage(1, 0, 0, 0);   // B0(0)
  stage(0, 0, 0, 0);   // A0(0)
  stage(0, 0, 1, 0);   // A1(0)
  stage(1, 0, 1, 0);   // B1(0)
  stage(1, 1, 0, 1);   // B0(1)
  stage(0, 1, 0, 1);   // A0(1)
  asm volatile("s_waitcnt vmcnt(4)" ::: "memory");
  BAR;

  const int iters = 8;   // K=1024, BK=64, 2 K-tiles per iter
#pragma unroll 1
  for (int it = 0; it < iters; ++it) {
    const int T = 2 * it;
    const bool pf = (it + 1 < iters);
    // ---- P0: tile T (dbuf0), m-half 0, both n-quadrants ----
    rdA(0, 0); rdB(0, 0); rdB(0, 1);
    stage(0, 1, 1, T + 1);                 // A1(T+1) -> dbuf1
    stage(1, 1, 1, T + 1);                 // B1(T+1) -> dbuf1
    BAR; PRIO1; mm(0, 0); mm(0, 1); PRIO0; BAR;
    // ---- P1: m-half 1; K-tile boundary drain ----
    rdA(0, 1);
    if (pf) { stage(1, 0, 0, T + 2);       // B0(T+2) -> dbuf0
              stage(0, 0, 0, T + 2); }     // A0(T+2) -> dbuf0
    BAR; PRIO1; mm(1, 0); mm(1, 1); PRIO0;
    if (pf) asm volatile("s_waitcnt vmcnt(4)" ::: "memory");
    else    asm volatile("s_waitcnt vmcnt(0)" ::: "memory");
    BAR;
    // ---- P2: tile T+1 (dbuf1), m-half 0 ----
    rdA(1, 0); rdB(1, 0); rdB(1, 1);
    if (pf) { stage(0, 0, 1, T + 2);       // A1(T+2) -> dbuf0
              stage(1, 0, 1, T + 2); }     // B1(T+2) -> dbuf0
    BAR; PRIO1; mm(0, 0); mm(0, 1); PRIO0; BAR;
    // ---- P3: m-half 1; K-tile boundary drain ----
    rdA(1, 1);
    if (pf) { stage(1, 1, 0, T + 3);       // B0(T+3) -> dbuf1
              stage(0, 1, 0, T + 3); }     // A0(T+3) -> dbuf1
    BAR; PRIO1; mm(1, 0); mm(1, 1); PRIO0;
    if (pf) asm volatile("s_waitcnt vmcnt(4)" ::: "memory");
    BAR;
  }
#undef BAR
#undef PRIO1
#undef PRIO0

  // epilogue: C row = (lane>>4)*4 + reg, col = lane&15 (m89-verified layout)
#pragma unroll
  for (int qm = 0; qm < 2; ++qm) {
#pragma unroll
    for (int qn = 0; qn < 2; ++qn) {
#pragma unroll
      for (int f = 0; f < 4; ++f) {
        const int r0 = bm * 256 + wm * 128 + qm * 64 + f * 16 + kg * 4;
#pragma unroll
        for (int n = 0; n < 2; ++n) {
          const int c = bn * 256 + wn * 64 + qn * 32 + n * 16 + arow;
          f32x4 v = acc[qm][qn][f][n];
#pragma unroll
          for (int r = 0; r < 4; ++r) {
            long idx = (long)(r0 + r) * ldc + c;
            if (EPI == 0) ((u16*)Cv)[idx] = f2bf(v[r]);
            else          ((float*)Cv)[idx] = v[r];
          }
        }
      }
    }
  }
}

extern "C" void kernel_launch(void* const* d_in, const int* in_sizes, int n_in,
                              void* d_out, int out_size, void* d_ws, size_t ws_size,
                              hipStream_t stream)
{
  (void)in_sizes; (void)n_in; (void)out_size; (void)ws_size;
  const int*   ids     = (const int*)d_in[0];
  const float* tok_emb = (const float*)d_in[1];
  const float* pos_emb = (const float*)d_in[2];
  const float* qkv_w   = (const float*)d_in[3];
  const float* o_w     = (const float*)d_in[4];
  const float* gate_w  = (const float*)d_in[5];
  const float* up_w    = (const float*)d_in[6];
  const float* down_w  = (const float*)d_in[7];
  const float* ln1_w   = (const float*)d_in[8];
  const float* ln1_b   = (const float*)d_in[9];
  const float* ln2_w   = (const float*)d_in[10];
  const float* ln2_b   = (const float*)d_in[11];
  const float* lnf_w   = (const float*)d_in[12];
  const float* lnf_b   = (const float*)d_in[13];
  const float* head_w  = (const float*)d_in[14];

  char* ws = (char*)d_ws;
  long off = 0;
  auto alloc = [&](long bytes) { void* p = ws + off; off += (bytes + 1023) & ~1023L; return p; };
  float* h   = (float*)alloc((long)TOK * HID * 4);
  u16*   x   = (u16*)  alloc((long)TOK * HID * 2);
  u16*   qkv = (u16*)  alloc((long)TOK * QKV3 * 2);
  u16*   vT  = (u16*)  alloc(32L * HDIM * SEQ * 2);
  u16*   ctx = (u16*)  alloc((long)TOK * HID * 2);
  u16*   y   = (u16*)  alloc((long)TOK * IPAD * 2);
  u16*   whead = (u16*)alloc((long)VOCAB * HID * 2);   // 65.5 MB; layer weights alias inside
  u16* wq  = whead;                       // 3072*1024
  u16* wo  = wq + 3072 * 1024;            // 1024*1024
  u16* wgu = wo + 1024 * 1024;            // 5632*1024 (interleaved gate/up rows)
  u16* wd  = wgu + 5632 * 1024;           // 1024*2816
  u16* scores = (u16*)d_out;              // 32*1024*1024 bf16 = 67 MB scratch in d_out

  embed_kernel<<<TOK, 256, 0, stream>>>(ids, tok_emb, pos_emb, h);

  for (int l = 0; l < NLAYER; ++l) {
    ln_kernel<<<TOK, 256, 0, stream>>>(h, ln1_w + l * HID, ln1_b + l * HID, x);

    cvt_kernel<<<1536, 256, 0, stream>>>(qkv_w + (long)l * QKV3 * HID, wq, QKV3, HID, HID, 393216L);
    gemm_bt<128, 128, 0><<<dim3(16, 24, 1), 256, 0, stream>>>(
        x, wq, qkv, nullptr, HID, HID, QKV3, HID, 1.f, 1, 0, 0, 0, 0, 0, 0);

    vtrans_kernel<<<1024, 256, 0, stream>>>(qkv, vT);

    // scores[z][q][k] = 0.125 * Q.K^T   (z = b*16+h)
    gemm_bt<128, 128, 0><<<dim3(8, 8, 32), 256, 0, stream>>>(
        qkv, qkv + 1024, scores, nullptr, QKV3, QKV3, 1024, 64, 0.125f,
        16, (long)SEQ * QKV3, 64L, (long)SEQ * QKV3, 64L, 16L * 1048576L, 1048576L);

    softmax_kernel<<<8192, 256, 0, stream>>>(scores);

    // ctx[b][q][h*64+d] = P @ V
    gemm_bt<128, 64, 0><<<dim3(8, 1, 32), 256, 0, stream>>>(
        scores, vT, ctx, nullptr, 1024, 1024, HID, 1024, 1.f,
        16, 16L * 1048576L, 1048576L, 16L * 65536L, 65536L, 1048576L, 64L);

    cvt_kernel<<<512, 256, 0, stream>>>(o_w + (long)l * HID * HID, wo, HID, HID, HID, 131072L);
    gemm_bt<64, 128, 2><<<dim3(32, 8, 1), 256, 0, stream>>>(
        ctx, wo, h, h, HID, HID, HID, HID, 1.f, 1, 0, 0, 0, 0, 0, 0);

    ln_kernel<<<TOK, 256, 0, stream>>>(h, ln2_w + l * HID, ln2_b + l * HID, x);

    cvt2i_kernel<<<2816, 256, 0, stream>>>(
        gate_w + (long)l * INTER * HID, up_w + (long)l * INTER * HID, wgu, 720896L);
    gemm_bt<128, 128, 3><<<dim3(16, 44, 1), 256, 0, stream>>>(
        x, wgu, y, nullptr, HID, HID, IPAD, HID, 1.f, 1, 0, 0, 0, 0, 0, 0);

    cvt_kernel<<<1408, 256, 0, stream>>>(down_w + (long)l * HID * INTER, wd, HID, INTER, IPAD, 360448L);
    gemm_bt<64, 128, 2><<<dim3(32, 8, 1), 256, 0, stream>>>(
        y, wd, h, h, IPAD, IPAD, HID, IPAD, 1.f, 1, 0, 0, 0, 0, 0, 0);
  }

  ln_kernel<<<TOK, 256, 0, stream>>>(h, lnf_w, lnf_b, x);
  cvt_kernel<<<16000, 256, 0, stream>>>(head_w, whead, VOCAB, HID, HID, 4096000L);
  gemm256<1><<<dim3(1000), 512, 0, stream>>>(x, whead, d_out, 125, VOCAB);
}

// Round 4
// 1551.399 us; speedup vs baseline: 1.1989x; 1.0616x over previous
//
#include <hip/hip_runtime.h>

typedef unsigned short u16;
typedef __attribute__((ext_vector_type(8))) short bf16x8;   // 8 bf16 (4 VGPR) MFMA frag
typedef __attribute__((ext_vector_type(8))) unsigned short us8;
typedef __attribute__((ext_vector_type(4))) unsigned short us4;
typedef __attribute__((ext_vector_type(4))) float f32x4;

#define SEQ    1024
#define TOK    2048           // B*S
#define HID    1024
#define NLAYER 6
#define NHEAD  16
#define HDIM   64
#define QKV3   3072
#define INTER  2730
#define IPAD   2816
#define VOCAB  32000
#define LN_EPS 1e-5f

__device__ __forceinline__ u16 f2bf(float f) {
  unsigned u = __float_as_uint(f);
  return (u16)((u + 0x7fffu + ((u >> 16) & 1u)) >> 16);   // RNE
}
__device__ __forceinline__ float bf2f(u16 u) {
  return __uint_as_float(((unsigned)u) << 16);
}

__device__ __forceinline__ void gl_lds16(const void* g, void* l) {
  __builtin_amdgcn_global_load_lds(
      (const __attribute__((address_space(1))) void*)g,
      (__attribute__((address_space(3))) void*)l, 16, 0, 0);
}

// ---------------- embedding: h = tok_emb[id] + pos_emb[s] (f32) ----------------
__global__ __launch_bounds__(256) void embed_kernel(
    const int* __restrict__ ids, const float* __restrict__ tok,
    const float* __restrict__ pos, float* __restrict__ h)
{
  int t = blockIdx.x;
  int s = t & (SEQ - 1);
  int id = ids[t];
  int c = threadIdx.x * 4;
  float4 tv = *(const float4*)(tok + (long)id * HID + c);
  float4 pv = *(const float4*)(pos + (long)s * HID + c);
  float4 o;
  o.x = tv.x + pv.x; o.y = tv.y + pv.y; o.z = tv.z + pv.z; o.w = tv.w + pv.w;
  *(float4*)(h + (long)t * HID + c) = o;
}

// ---------------- layernorm: f32 in -> bf16 out ----------------
__global__ __launch_bounds__(256) void ln_kernel(
    const float* __restrict__ h, const float* __restrict__ w,
    const float* __restrict__ b, u16* __restrict__ out)
{
  int t = blockIdx.x;
  int tid = threadIdx.x;
  int lane = tid & 63, wid = tid >> 6;
  float4 v = *(const float4*)(h + (long)t * HID + tid * 4);
  float s1 = v.x + v.y + v.z + v.w;
  float s2 = v.x * v.x + v.y * v.y + v.z * v.z + v.w * v.w;
#pragma unroll
  for (int o = 32; o > 0; o >>= 1) { s1 += __shfl_down(s1, o); s2 += __shfl_down(s2, o); }
  __shared__ float r1[4], r2[4];
  if (lane == 0) { r1[wid] = s1; r2[wid] = s2; }
  __syncthreads();
  float t1 = r1[0] + r1[1] + r1[2] + r1[3];
  float t2 = r2[0] + r2[1] + r2[2] + r2[3];
  float mu = t1 * (1.f / HID);
  float var = t2 * (1.f / HID) - mu * mu;
  float rs = rsqrtf(var + LN_EPS);
  float4 wv = *(const float4*)(w + tid * 4);
  float4 bv = *(const float4*)(b + tid * 4);
  us4 o4;
  o4[0] = f2bf((v.x - mu) * rs * wv.x + bv.x);
  o4[1] = f2bf((v.y - mu) * rs * wv.y + bv.y);
  o4[2] = f2bf((v.z - mu) * rs * wv.z + bv.z);
  o4[3] = f2bf((v.w - mu) * rs * wv.w + bv.w);
  *(us4*)(out + (long)t * HID + tid * 4) = o4;
}

// ---------------- f32 -> bf16 weight convert with zero padding ----------------
__global__ __launch_bounds__(256) void cvt_kernel(
    const float* __restrict__ src, u16* __restrict__ dst,
    int N, int K, int Kpad, long total8)
{
  long i = (long)blockIdx.x * 256 + threadIdx.x;
  if (i >= total8) return;
  int kp8 = Kpad >> 3;
  int n = (int)(i / kp8);
  int kc = (int)(i % kp8);
  us8 o;
#pragma unroll
  for (int j = 0; j < 8; ++j) {
    int k = kc * 8 + j;
    float v = (n < N && k < K) ? src[(long)n * K + k] : 0.f;
    o[j] = f2bf(v);
  }
  *(us8*)(dst + i * 8) = o;
}

// -------- interleaved gate/up convert: dst row 2g = gate[g], 2g+1 = up[g] --------
__global__ __launch_bounds__(256) void cvt2i_kernel(
    const float* __restrict__ gate, const float* __restrict__ up,
    u16* __restrict__ dst, long total8)
{
  long i = (long)blockIdx.x * 256 + threadIdx.x;   // 5632*128
  if (i >= total8) return;
  int n  = (int)(i >> 7);        // interleaved row 0..5631
  int kc = (int)(i & 127);
  int g  = n >> 1;
  const float* src = (n & 1) ? up : gate;
  us8 o;
#pragma unroll
  for (int j = 0; j < 8; ++j) {
    int k = kc * 8 + j;
    float v = (g < INTER) ? src[(long)g * HID + k] : 0.f;
    o[j] = f2bf(v);
  }
  *(us8*)(dst + i * 8) = o;
}

// ---------------- V transpose: vT[z][d][k] = qkv[b][k][2048 + h*64 + d] ----------------
__global__ __launch_bounds__(256) void vtrans_kernel(
    const u16* __restrict__ qkv, u16* __restrict__ vT)
{
  int gid = blockIdx.x * 256 + threadIdx.x;     // 32*64*128 total
  int d  = gid & 63;
  int kc = (gid >> 6) & 127;
  int z  = gid >> 13;                           // b*16+h
  int b = z >> 4, hh = z & 15;
  const u16* src = qkv + (long)b * SEQ * QKV3 + 2048 + hh * 64 + d;
  us8 v;
#pragma unroll
  for (int j = 0; j < 8; ++j) v[j] = src[(long)(kc * 8 + j) * QKV3];
  *(us8*)(vT + (long)z * 65536 + (long)d * 1024 + kc * 8) = v;
}

// ---------------- fused flash attention ----------------
// Grid (8, 32): blockIdx.x = q-tile (128 rows), blockIdx.y = z = b*16+h.
// 256 thr = 4 waves; wave w owns 32 q-rows.  Loop over 8 kv-chunks of 128:
// S = 0.125*Q.K^T (MFMA) -> online softmax (f32 regs) -> P bf16 via per-wave
// LDS (XOR-swizzled, G4) -> O += P.V (MFMA, V from vT).  K/V staged via
// global_load_lds into conflict-free K-major LDS (layout proven in gemm256).
__global__ __launch_bounds__(256, 2) void attn_kernel(
    const u16* __restrict__ qkv, const u16* __restrict__ vT,
    u16* __restrict__ ctx)
{
  __shared__ u16 Ks[8][128][8];     // [d-grp][kseq][8d]  16 KB; unit addr = g*128+row
  __shared__ u16 Vs[16][64][8];     // [k-grp][d][8k]     16 KB; unit addr = kg*64+d
  __shared__ u16 Ps[4][32 * 128];   // per-wave P tile    32 KB (row stride 256 B)

  const int tid  = threadIdx.x;
  const int lane = tid & 63;
  const int w    = tid >> 6;
  const int lo   = lane & 15;
  const int hi   = lane >> 4;

  const int qt = blockIdx.x;
  const int z  = blockIdx.y;
  const int b  = z >> 4, h = z & 15;

  const u16* Qb  = qkv + (long)b * SEQ * QKV3 + h * 64;
  const u16* Kb  = Qb + 1024;
  const u16* Vtb = vT + (long)z * 65536;

  // Q fragments direct to regs: row = qt*128+w*32+i*16+lo, k = ks*32+hi*8
  bf16x8 q[2][2];
#pragma unroll
  for (int i = 0; i < 2; ++i)
#pragma unroll
    for (int ks = 0; ks < 2; ++ks)
      q[i][ks] = *(const bf16x8*)(Qb + (long)(qt * 128 + w * 32 + i * 16 + lo) * QKV3
                                  + ks * 32 + hi * 8);

  f32x4 po[2][4];
  float m_run[2][4], l_run[2][4];
#pragma unroll
  for (int i = 0; i < 2; ++i)
#pragma unroll
    for (int r = 0; r < 4; ++r) { m_run[i][r] = -1e30f; l_run[i][r] = 0.f; }
#pragma unroll
  for (int i = 0; i < 2; ++i)
#pragma unroll
    for (int nd = 0; nd < 4; ++nd) po[i][nd] = (f32x4){0.f, 0.f, 0.f, 0.f};

  char* Pw = (char*)&Ps[w][0];

  for (int c = 0; c < 8; ++c) {
    // ---- stage K (16 units) and V (16 units); unit = w*4+i ----
#pragma unroll
    for (int i = 0; i < 4; ++i) {
      int u = w * 4 + i, g = u & 7, rg = u >> 3;
      gl_lds16(Kb + (long)(c * 128 + rg * 64 + lane) * QKV3 + g * 8, &Ks[g][rg * 64][0]);
    }
#pragma unroll
    for (int i = 0; i < 4; ++i) {
      int kg = w * 4 + i;
      gl_lds16(Vtb + (long)lane * 1024 + c * 128 + kg * 8, &Vs[kg][0][0]);
    }
    __syncthreads();   // drains vmcnt+lgkmcnt

    // ---- S = Q.K^T : rows 32 (i,hi,r), cols 128 (jf,lo) ----
    f32x4 s[2][8];
#pragma unroll
    for (int i = 0; i < 2; ++i)
#pragma unroll
      for (int jf = 0; jf < 8; ++jf) s[i][jf] = (f32x4){0.f, 0.f, 0.f, 0.f};
#pragma unroll
    for (int jf = 0; jf < 8; ++jf) {
      bf16x8 bk[2];
#pragma unroll
      for (int ks = 0; ks < 2; ++ks)
        bk[ks] = *(const bf16x8*)&Ks[ks * 4 + hi][jf * 16 + lo][0];
#pragma unroll
      for (int i = 0; i < 2; ++i)
#pragma unroll
        for (int ks = 0; ks < 2; ++ks)
          s[i][jf] = __builtin_amdgcn_mfma_f32_16x16x32_bf16(q[i][ks], bk[ks], s[i][jf], 0, 0, 0);
    }

    // ---- online softmax (scale 0.125 folded in) ----
    float scf[2][4];
#pragma unroll
    for (int i = 0; i < 2; ++i) {
#pragma unroll
      for (int r = 0; r < 4; ++r) {
        float rm = -1e30f;
#pragma unroll
        for (int jf = 0; jf < 8; ++jf) {
          s[i][jf][r] *= 0.125f;
          rm = fmaxf(rm, s[i][jf][r]);
        }
#pragma unroll
        for (int o = 1; o < 16; o <<= 1) rm = fmaxf(rm, __shfl_xor(rm, o));
        float mn = fmaxf(m_run[i][r], rm);
        float sc = __expf(m_run[i][r] - mn);
        float rs = 0.f;
#pragma unroll
        for (int jf = 0; jf < 8; ++jf) {
          float e = __expf(s[i][jf][r] - mn);
          s[i][jf][r] = e;
          rs += e;
        }
#pragma unroll
        for (int o = 1; o < 16; o <<= 1) rs += __shfl_xor(rs, o);
        l_run[i][r] = l_run[i][r] * sc + rs;
        m_run[i][r] = mn;
        scf[i][r] = sc;
      }
    }

    // ---- write P (bf16) to per-wave LDS, XOR-swizzled; rescale O ----
#pragma unroll
    for (int i = 0; i < 2; ++i)
#pragma unroll
      for (int jf = 0; jf < 8; ++jf)
#pragma unroll
        for (int r = 0; r < 4; ++r) {
          int row = i * 16 + hi * 4 + r;
          int byo = row * 256 + ((((jf * 16 + lo) * 2)) ^ ((row & 7) << 4));
          *(u16*)(Pw + byo) = f2bf(s[i][jf][r]);
        }
#pragma unroll
    for (int i = 0; i < 2; ++i)
#pragma unroll
      for (int nd = 0; nd < 4; ++nd)
#pragma unroll
        for (int r = 0; r < 4; ++r) po[i][nd][r] *= scf[i][r];

    // ---- O += P.V ----  (compiler orders the LDS write->read)
    bf16x8 pa[2][4];
#pragma unroll
    for (int i = 0; i < 2; ++i)
#pragma unroll
      for (int ks2 = 0; ks2 < 4; ++ks2) {
        int row = i * 16 + lo;
        int byo = row * 256 + (((ks2 * 32 + hi * 8) * 2) ^ ((row & 7) << 4));
        pa[i][ks2] = *(const bf16x8*)(Pw + byo);
      }
#pragma unroll
    for (int nd = 0; nd < 4; ++nd) {
      bf16x8 bv[4];
#pragma unroll
      for (int ks2 = 0; ks2 < 4; ++ks2)
        bv[ks2] = *(const bf16x8*)&Vs[ks2 * 4 + hi][nd * 16 + lo][0];
#pragma unroll
      for (int i = 0; i < 2; ++i)
#pragma unroll
        for (int ks2 = 0; ks2 < 4; ++ks2)
          po[i][nd] = __builtin_amdgcn_mfma_f32_16x16x32_bf16(pa[i][ks2], bv[ks2], po[i][nd], 0, 0, 0);
    }
    __syncthreads();   // protect Ks/Vs before next stage
  }

  // ---- finalize: O/l -> ctx ----
#pragma unroll
  for (int i = 0; i < 2; ++i) {
#pragma unroll
    for (int r = 0; r < 4; ++r) {
      float inv = 1.f / l_run[i][r];
      int qrow = qt * 128 + w * 32 + i * 16 + hi * 4 + r;
      u16* dst = ctx + (long)(b * SEQ + qrow) * HID + h * 64;
#pragma unroll
      for (int nd = 0; nd < 4; ++nd)
        dst[nd * 16 + lo] = f2bf(po[i][nd][r] * inv);
    }
  }
}

// ---------------- GEMM: C[m,n] = scale * sum_k A[m,k]*B[n,k] (+resid) ----------------
// A: [M][K] bf16 row-major (lda), B: [N][K] bf16 row-major (ldb).
// EPI: 0 = bf16 out (xscale), 1 = f32 out (xscale), 2 = f32 resid add,
//      3 = fused silu (B rows interleaved gate/up; see r3).
template<int BM, int BN, int EPI>
__global__ __launch_bounds__(256) void gemm_bt(
    const u16* __restrict__ A, const u16* __restrict__ B,
    void* __restrict__ Cv, const float* __restrict__ resid,
    int lda, int ldb, int ldc, int K, float scale, int bdiv,
    long sA1, long sA2, long sB1, long sB2, long sC1, long sC2)
{
  constexpr int FM = BM / 32;
  constexpr int FN = BN / 32;
  __shared__ u16 As[2][BM * 32];
  __shared__ u16 Bs[2][BN * 32];

  const int tid = threadIdx.x;
  const int lane = tid & 63;
  const int wid = tid >> 6;
  const int wm = wid >> 1, wn = wid & 1;

  const int z = blockIdx.z;
  const long offA = (long)(z / bdiv) * sA1 + (long)(z % bdiv) * sA2;
  const long offB = (long)(z / bdiv) * sB1 + (long)(z % bdiv) * sB2;
  const long offC = (long)(z / bdiv) * sC1 + (long)(z % bdiv) * sC2;

  const u16* Ab = A + offA + (long)blockIdx.x * BM * lda;
  const u16* Bb = B + offB + (long)blockIdx.y * BN * ldb;

  auto stage = [&](int buf, int kt) {
    const u16* a = Ab + (long)kt * 32;
    const u16* bsrc = Bb + (long)kt * 32;
#pragma unroll
    for (int i = 0; i < BM / 64; ++i) {
      int row = i * 64 + wid * 16 + (lane >> 2);
      gl_lds16(a + (long)row * lda + (lane & 3) * 8, &As[buf][i * 2048 + wid * 512]);
    }
#pragma unroll
    for (int i = 0; i < BN / 64; ++i) {
      int row = i * 64 + wid * 16 + (lane >> 2);
      gl_lds16(bsrc + (long)row * ldb + (lane & 3) * 8, &Bs[buf][i * 2048 + wid * 512]);
    }
  };

  f32x4 acc[FM][FN];
#pragma unroll
  for (int i = 0; i < FM; ++i)
#pragma unroll
    for (int j = 0; j < FN; ++j) acc[i][j] = (f32x4){0.f, 0.f, 0.f, 0.f};

  int aoff[FM], boff[FN];
#pragma unroll
  for (int i = 0; i < FM; ++i)
    aoff[i] = (wm * (BM / 2) + i * 16 + (lane & 15)) * 32 + (lane >> 4) * 8;
#pragma unroll
  for (int j = 0; j < FN; ++j)
    boff[j] = (wn * (BN / 2) + j * 16 + (lane & 15)) * 32 + (lane >> 4) * 8;

  const int KT = K >> 5;
  stage(0, 0);
  __syncthreads();
  int cur = 0;
  for (int kt = 0; kt < KT; ++kt) {
    if (kt + 1 < KT) stage(cur ^ 1, kt + 1);
    bf16x8 av[FM], bv[FN];
#pragma unroll
    for (int i = 0; i < FM; ++i) av[i] = *(const bf16x8*)&As[cur][aoff[i]];
#pragma unroll
    for (int j = 0; j < FN; ++j) bv[j] = *(const bf16x8*)&Bs[cur][boff[j]];
#pragma unroll
    for (int i = 0; i < FM; ++i)
#pragma unroll
      for (int j = 0; j < FN; ++j)
        acc[i][j] = __builtin_amdgcn_mfma_f32_16x16x32_bf16(av[i], bv[j], acc[i][j], 0, 0, 0);
    __syncthreads();
    cur ^= 1;
  }

  const int r0 = blockIdx.x * BM + wm * (BM / 2) + (lane >> 4) * 4;
  const int c0 = blockIdx.y * BN + wn * (BN / 2) + (lane & 15);
#pragma unroll
  for (int i = 0; i < FM; ++i) {
#pragma unroll
    for (int j = 0; j < FN; ++j) {
      f32x4 v = acc[i][j];
#pragma unroll
      for (int r = 0; r < 4; ++r) {
        if (EPI == 3) {
          float pv = __shfl_xor(v[r], 1);
          if ((lane & 1) == 0) {
            float gf = v[r];
            float res = gf / (1.f + __expf(-gf)) * pv;
            int cc = c0 + j * 16;
            long idx = offC + (long)(r0 + i * 16 + r) * ldc + (cc >> 1);
            ((u16*)Cv)[idx] = f2bf(res);
          }
        } else {
          long idx = offC + (long)(r0 + i * 16 + r) * ldc + (c0 + j * 16);
          if (EPI == 0)       ((u16*)Cv)[idx] = f2bf(v[r] * scale);
          else if (EPI == 1)  ((float*)Cv)[idx] = v[r] * scale;
          else                ((float*)Cv)[idx] = resid[idx] + v[r];
        }
      }
    }
  }
}

// ---------------- gemm256: 256x256 tile, BK=64, 4 merged phases/iter (see r2/r3) ----------------
template<int EPI>
__global__ __launch_bounds__(512, 1) void gemm256(
    const u16* __restrict__ A, const u16* __restrict__ B,
    void* __restrict__ Cv, int NB, int ldc)
{
  __shared__ u16 lds[2][2][2][8][128][8];   // [dbuf][mat][half][kg][row][8] = 128 KiB

  const int tid  = threadIdx.x;
  const int lane = tid & 63;
  const int w    = tid >> 6;
  const int wm   = w >> 2;
  const int wn   = w & 3;
  const int arow = lane & 15;
  const int kg   = lane >> 4;

  const int flat = blockIdx.x;
  const int swz  = (flat & 7) * NB + (flat >> 3);
  const int bm   = swz & 7;
  const int bn   = swz >> 3;

  const u16* Ab = A + (long)bm * 256 * 1024;
  const u16* Bb = B + (long)bn * 256 * 1024;

  auto stage = [&](int mat, int d, int half, int t) {
#pragma unroll
    for (int i = 0; i < 2; ++i) {
      const int u  = w * 2 + i;
      const int g  = u & 7;
      const int rg = u >> 3;
      const u16* src = (mat == 0 ? Ab : Bb)
                     + (long)(half * 128 + rg * 64 + lane) * 1024 + t * 64 + g * 8;
      gl_lds16(src, &lds[d][mat][half][g][rg * 64][0]);
    }
  };

  f32x4 acc[2][2][4][2];
#pragma unroll
  for (int qm = 0; qm < 2; ++qm)
#pragma unroll
    for (int qn = 0; qn < 2; ++qn)
#pragma unroll
      for (int f = 0; f < 4; ++f)
#pragma unroll
        for (int n = 0; n < 2; ++n) acc[qm][qn][f][n] = (f32x4){0.f, 0.f, 0.f, 0.f};

  bf16x8 a[4][2];
  bf16x8 b[2][2][2];

  auto rdA = [&](int d, int qm) {
#pragma unroll
    for (int f = 0; f < 4; ++f)
#pragma unroll
      for (int ks = 0; ks < 2; ++ks)
        a[f][ks] = *(const bf16x8*)&lds[d][0][wm][ks * 4 + kg][qm * 64 + f * 16 + arow][0];
  };
  auto rdB = [&](int d, int qn) {
#pragma unroll
    for (int n = 0; n < 2; ++n)
#pragma unroll
      for (int ks = 0; ks < 2; ++ks)
        b[qn][n][ks] = *(const bf16x8*)&lds[d][1][wn >> 1][ks * 4 + kg]
                                          [(wn & 1) * 64 + qn * 32 + n * 16 + arow][0];
  };
  auto mm = [&](int qm, int qn) {
#pragma unroll
    for (int f = 0; f < 4; ++f)
#pragma unroll
      for (int n = 0; n < 2; ++n)
#pragma unroll
        for (int ks = 0; ks < 2; ++ks)
          acc[qm][qn][f][n] = __builtin_amdgcn_mfma_f32_16x16x32_bf16(
              a[f][ks], b[qn][n][ks], acc[qm][qn][f][n], 0, 0, 0);
  };

#define BAR asm volatile("s_barrier" ::: "memory")
#define PRIO1 __builtin_amdgcn_s_setprio(1)
#define PRIO0 __builtin_amdgcn_s_setprio(0)

  stage(1, 0, 0, 0);
  stage(0, 0, 0, 0);
  stage(0, 0, 1, 0);
  stage(1, 0, 1, 0);
  stage(1, 1, 0, 1);
  stage(0, 1, 0, 1);
  asm volatile("s_waitcnt vmcnt(4)" ::: "memory");
  BAR;

  const int iters = 8;
#pragma unroll 1
  for (int it = 0; it < iters; ++it) {
    const int T = 2 * it;
    const bool pf = (it + 1 < iters);
    rdA(0, 0); rdB(0, 0); rdB(0, 1);
    stage(0, 1, 1, T + 1);
    stage(1, 1, 1, T + 1);
    BAR; PRIO1; mm(0, 0); mm(0, 1); PRIO0; BAR;
    rdA(0, 1);
    if (pf) { stage(1, 0, 0, T + 2);
              stage(0, 0, 0, T + 2); }
    BAR; PRIO1; mm(1, 0); mm(1, 1); PRIO0;
    if (pf) asm volatile("s_waitcnt vmcnt(4)" ::: "memory");
    else    asm volatile("s_waitcnt vmcnt(0)" ::: "memory");
    BAR;
    rdA(1, 0); rdB(1, 0); rdB(1, 1);
    if (pf) { stage(0, 0, 1, T + 2);
              stage(1, 0, 1, T + 2); }
    BAR; PRIO1; mm(0, 0); mm(0, 1); PRIO0; BAR;
    rdA(1, 1);
    if (pf) { stage(1, 1, 0, T + 3);
              stage(0, 1, 0, T + 3); }
    BAR; PRIO1; mm(1, 0); mm(1, 1); PRIO0;
    if (pf) asm volatile("s_waitcnt vmcnt(4)" ::: "memory");
    BAR;
  }
#undef BAR
#undef PRIO1
#undef PRIO0

#pragma unroll
  for (int qm = 0; qm < 2; ++qm) {
#pragma unroll
    for (int qn = 0; qn < 2; ++qn) {
#pragma unroll
      for (int f = 0; f < 4; ++f) {
        const int r0 = bm * 256 + wm * 128 + qm * 64 + f * 16 + kg * 4;
#pragma unroll
        for (int n = 0; n < 2; ++n) {
          const int c = bn * 256 + wn * 64 + qn * 32 + n * 16 + arow;
          f32x4 v = acc[qm][qn][f][n];
#pragma unroll
          for (int r = 0; r < 4; ++r) {
            long idx = (long)(r0 + r) * ldc + c;
            if (EPI == 0) ((u16*)Cv)[idx] = f2bf(v[r]);
            else          ((float*)Cv)[idx] = v[r];
          }
        }
      }
    }
  }
}

extern "C" void kernel_launch(void* const* d_in, const int* in_sizes, int n_in,
                              void* d_out, int out_size, void* d_ws, size_t ws_size,
                              hipStream_t stream)
{
  (void)in_sizes; (void)n_in; (void)out_size; (void)ws_size;
  const int*   ids     = (const int*)d_in[0];
  const float* tok_emb = (const float*)d_in[1];
  const float* pos_emb = (const float*)d_in[2];
  const float* qkv_w   = (const float*)d_in[3];
  const float* o_w     = (const float*)d_in[4];
  const float* gate_w  = (const float*)d_in[5];
  const float* up_w    = (const float*)d_in[6];
  const float* down_w  = (const float*)d_in[7];
  const float* ln1_w   = (const float*)d_in[8];
  const float* ln1_b   = (const float*)d_in[9];
  const float* ln2_w   = (const float*)d_in[10];
  const float* ln2_b   = (const float*)d_in[11];
  const float* lnf_w   = (const float*)d_in[12];
  const float* lnf_b   = (const float*)d_in[13];
  const float* head_w  = (const float*)d_in[14];

  char* ws = (char*)d_ws;
  long off = 0;
  auto alloc = [&](long bytes) { void* p = ws + off; off += (bytes + 1023) & ~1023L; return p; };
  float* h   = (float*)alloc((long)TOK * HID * 4);
  u16*   x   = (u16*)  alloc((long)TOK * HID * 2);
  u16*   qkv = (u16*)  alloc((long)TOK * QKV3 * 2);
  u16*   vT  = (u16*)  alloc(32L * HDIM * SEQ * 2);
  u16*   ctx = (u16*)  alloc((long)TOK * HID * 2);
  u16*   y   = (u16*)  alloc((long)TOK * IPAD * 2);
  u16*   whead = (u16*)alloc((long)VOCAB * HID * 2);   // 65.5 MB; layer weights alias inside
  u16* wq  = whead;                       // 3072*1024
  u16* wo  = wq + 3072 * 1024;            // 1024*1024
  u16* wgu = wo + 1024 * 1024;            // 5632*1024 (interleaved gate/up rows)
  u16* wd  = wgu + 5632 * 1024;           // 1024*2816

  embed_kernel<<<TOK, 256, 0, stream>>>(ids, tok_emb, pos_emb, h);

  for (int l = 0; l < NLAYER; ++l) {
    ln_kernel<<<TOK, 256, 0, stream>>>(h, ln1_w + l * HID, ln1_b + l * HID, x);

    cvt_kernel<<<1536, 256, 0, stream>>>(qkv_w + (long)l * QKV3 * HID, wq, QKV3, HID, HID, 393216L);
    gemm_bt<128, 128, 0><<<dim3(16, 24, 1), 256, 0, stream>>>(
        x, wq, qkv, nullptr, HID, HID, QKV3, HID, 1.f, 1, 0, 0, 0, 0, 0, 0);

    vtrans_kernel<<<1024, 256, 0, stream>>>(qkv, vT);

    // fused flash attention: qkv -> ctx
    attn_kernel<<<dim3(8, 32), 256, 0, stream>>>(qkv, vT, ctx);

    cvt_kernel<<<512, 256, 0, stream>>>(o_w + (long)l * HID * HID, wo, HID, HID, HID, 131072L);
    gemm_bt<64, 128, 2><<<dim3(32, 8, 1), 256, 0, stream>>>(
        ctx, wo, h, h, HID, HID, HID, HID, 1.f, 1, 0, 0, 0, 0, 0, 0);

    ln_kernel<<<TOK, 256, 0, stream>>>(h, ln2_w + l * HID, ln2_b + l * HID, x);

    cvt2i_kernel<<<2816, 256, 0, stream>>>(
        gate_w + (long)l * INTER * HID, up_w + (long)l * INTER * HID, wgu, 720896L);
    gemm_bt<128, 128, 3><<<dim3(16, 44, 1), 256, 0, stream>>>(
        x, wgu, y, nullptr, HID, HID, IPAD, HID, 1.f, 1, 0, 0, 0, 0, 0, 0);

    cvt_kernel<<<1408, 256, 0, stream>>>(down_w + (long)l * HID * INTER, wd, HID, INTER, IPAD, 360448L);
    gemm_bt<64, 128, 2><<<dim3(32, 8, 1), 256, 0, stream>>>(
        y, wd, h, h, IPAD, IPAD, HID, IPAD, 1.f, 1, 0, 0, 0, 0, 0, 0);
  }

  ln_kernel<<<TOK, 256, 0, stream>>>(h, lnf_w, lnf_b, x);
  cvt_kernel<<<16000, 256, 0, stream>>>(head_w, whead, VOCAB, HID, HID, 4096000L);
  gemm256<1><<<dim3(1000), 512, 0, stream>>>(x, whead, d_out, 125, VOCAB);
}